// Round 9
// baseline (1875.607 us; speedup 1.0000x reference)
//
#include <hip/hip_runtime.h>
#include <math.h>

typedef float  floatx4  __attribute__((ext_vector_type(4)));
typedef _Float16 half8  __attribute__((ext_vector_type(8)));
typedef _Float16 half4  __attribute__((ext_vector_type(4)));

// ---------- MFMA 16x16x32 f16 ----------
// A-frag: lane l holds A[l&15][(l>>4)*8+j]; B-frag: lane l holds B[(l>>4)*8+j][l&15]
// C/D: lane l reg r = D[(l>>4)*4+r][l&15]   (verified rounds 1-8)
__device__ inline floatx4 mfma_f16(half8 a, half8 b, floatx4 c){
  return __builtin_amdgcn_mfma_f32_16x16x32_f16(a, b, c, 0, 0, 0);
}

// ---------- async global->LDS, 16B per lane ----------
__device__ inline void gld_lds16(const void* g, void* l){
  __builtin_amdgcn_global_load_lds(
      (const __attribute__((address_space(1))) unsigned int*)g,
      (__attribute__((address_space(3))) unsigned int*)l, 16, 0, 0);
}

// =======================================================================
// fp16 GEMM, 128 threads (2 waves), tile BM=64 x BN=128, wave-tile 64x64.
// MR=4, NR=4 -> 16 MFMA : 8 ds_read_b128 per wave-K-step (2:1).
// Double-buffered LDS (24KB -> 6 blocks/CU), gld_lds staging, XOR swizzle,
// XCD-chunked block swizzle. KSPLIT>1 -> f32 partials.
// Modes: 0 outf=acc+bias; 4 gate/up silu->fp16; 5 outp=acc+bias fp16.
// =======================================================================
template<int MODE, int KSPLIT>
__global__ __launch_bounds__(128) void gemm_f16(
    const _Float16* __restrict__ A, const _Float16* __restrict__ W,
    const float* __restrict__ bias,
    float* __restrict__ outf, _Float16* __restrict__ outp,
    int K, int Nout, int Mtot, float* __restrict__ part)
{
  constexpr int BM = 64, BN = 128;
  __shared__ _Float16 SA[2][BM*32];
  __shared__ _Float16 SW[2][BN*32];
  const int tid = threadIdx.x, lane = tid & 63, wv = tid >> 6;

  int m_idx, n_idx;
  {
    const int gx = gridDim.x, gy = gridDim.y;
    const int T = gx * gy;
    int id = blockIdx.y * gx + blockIdx.x;
    if ((T & 7) == 0){
      int wg = (id & 7) * (T >> 3) + (id >> 3);
      n_idx = wg / gy; m_idx = wg - n_idx * gy;
    } else { n_idx = blockIdx.x; m_idx = blockIdx.y; }
  }
  const int m0 = m_idx * BM, n0 = n_idx * BN;
  const int kbase = (KSPLIT > 1) ? blockIdx.z * (K / KSPLIT) : 0;
  floatx4 acc[4][4];
  #pragma unroll
  for (int mr = 0; mr < 4; mr++)
    #pragma unroll
    for (int nr = 0; nr < 4; nr++) acc[mr][nr] = 0.f;
  const int fr = lane & 15, kg = lane >> 4;

  auto stage = [&](int buf, int k0){
    #pragma unroll
    for (int p = 0; p < 2; p++){            // A: 64 rows x 4 granules
      int lin = p * 128 + tid;
      int row = lin >> 2, gg = (lin & 3) ^ ((row >> 1) & 3);
      size_t go = (size_t)(m0 + row) * K + kbase + k0 + gg * 8;
      gld_lds16(A + go, &SA[buf][(p * 128 + wv * 64) * 8]);
    }
    #pragma unroll
    for (int p = 0; p < 4; p++){            // W: 128 rows x 4 granules
      int lin = p * 128 + tid;
      int row = lin >> 2, gg = (lin & 3) ^ ((row >> 1) & 3);
      size_t go = (size_t)(n0 + row) * K + kbase + k0 + gg * 8;
      gld_lds16(W + go, &SW[buf][(p * 128 + wv * 64) * 8]);
    }
  };

  stage(0, 0);
  __syncthreads();
  const int nt = (K / KSPLIT) >> 5;
  for (int t = 0; t < nt; t++){
    const int buf = t & 1;
    if (t + 1 < nt) stage(buf ^ 1, (t + 1) << 5);
    half8 af[4], wf[4];
    #pragma unroll
    for (int mr = 0; mr < 4; mr++){
      int r = mr * 16 + fr;
      int off = r * 64 + ((kg ^ ((r >> 1) & 3)) << 4);
      af[mr] = *(const half8*)((const char*)&SA[buf][0] + off);
    }
    #pragma unroll
    for (int nr = 0; nr < 4; nr++){
      int r = wv * 64 + nr * 16 + fr;
      int off = r * 64 + ((kg ^ ((r >> 1) & 3)) << 4);
      wf[nr] = *(const half8*)((const char*)&SW[buf][0] + off);
    }
    #pragma unroll
    for (int mr = 0; mr < 4; mr++)
      #pragma unroll
      for (int nr = 0; nr < 4; nr++)
        acc[mr][nr] = mfma_f16(af[mr], wf[nr], acc[mr][nr]);
    __syncthreads();
  }
  #pragma unroll
  for (int mr = 0; mr < 4; mr++)
    #pragma unroll
    for (int nr = 0; nr < 4; nr++){
      int np = n0 + wv * 64 + nr * 16 + fr;
      #pragma unroll
      for (int e = 0; e < 4; e++){
        int row = m0 + mr * 16 + kg * 4 + e;
        float v = acc[mr][nr][e];
        if (KSPLIT > 1){
          part[((size_t)blockIdx.z * Mtot + row) * Nout + np] = v;
        } else {
          v += bias ? bias[np] : 0.f;
          if (MODE == 0) outf[(size_t)row * Nout + np] = v;
          if (MODE == 5) outp[(size_t)row * Nout + np] = (_Float16)v;
          if (MODE == 4){
            float pv = __shfl_xor(v, 1);
            if (!(fr & 1)){
              float dv = v / (1.f + __expf(-v)) * pv;
              outp[(size_t)row * (Nout >> 1) + (np >> 1)] = (_Float16)dv;
            }
          }
        }
      }
    }
}

// =======================================================================
// Fused split-K reduce (+bias +res) -> H (f32) -> RMSNorm -> fp16 plane.
// One block per row; M=1024, N=1280 fixed.
// =======================================================================
__global__ __launch_bounds__(256) void reduce_rms(
    const float* __restrict__ part, int Z,
    const float* __restrict__ bias, const float* __restrict__ res,
    float* __restrict__ Hout, const float* __restrict__ w,
    _Float16* __restrict__ ANp)
{
  const int row = blockIdx.x;
  float v[5];
  float ss = 0.f;
  #pragma unroll
  for (int j = 0; j < 5; j++){
    int col = threadIdx.x + j * 256;
    float t = part[(size_t)row * 1280 + col];
    for (int z = 1; z < Z; z++)
      t += part[((size_t)z * 1024 + row) * 1280 + col];
    if (bias) t += bias[col];
    if (res)  t += res[(size_t)row * 1280 + col];
    v[j] = t;
    Hout[(size_t)row * 1280 + col] = t;
    ss = fmaf(t, t, ss);
  }
  for (int o = 32; o > 0; o >>= 1) ss += __shfl_down(ss, o);
  __shared__ float wsum[4];
  __shared__ float snorm;
  if ((threadIdx.x & 63) == 0) wsum[threadIdx.x >> 6] = ss;
  __syncthreads();
  if (threadIdx.x == 0){
    float t = wsum[0] + wsum[1] + wsum[2] + wsum[3];
    snorm = 1.0f / sqrtf(t * (1.0f / 1280.0f) + 1e-6f);
  }
  __syncthreads();
  float s = snorm;
  #pragma unroll
  for (int j = 0; j < 5; j++){
    int col = threadIdx.x + j * 256;
    ANp[(size_t)row * 1280 + col] = (_Float16)(v[j] * s * w[col]);
  }
}

// =======================================================================
// Generic split-K reduce + epilogue (merger). part[z][M][N] f32.
// MODE 2: outp(fp16) = gelu_exact(sum + bias)
// MODE 3: outf[rowmap[row]*N + col] = sum + bias
// =======================================================================
template<int MODE>
__global__ __launch_bounds__(256) void reduce_k(
    const float* __restrict__ part, int Z, int M, int N,
    const float* __restrict__ bias,
    float* __restrict__ outf, _Float16* __restrict__ outp,
    const int* __restrict__ rowmap)
{
  int idx4 = (blockIdx.x * 256 + threadIdx.x) * 4;
  if (idx4 >= M * N) return;
  int row = idx4 / N, col = idx4 - row * N;
  floatx4 v = *(const floatx4*)(part + (size_t)row * N + col);
  for (int z = 1; z < Z; z++){
    floatx4 p = *(const floatx4*)(part + ((size_t)z * M + row) * N + col);
    v[0] += p[0]; v[1] += p[1]; v[2] += p[2]; v[3] += p[3];
  }
  if (bias){
    floatx4 b = *(const floatx4*)(bias + col);
    v[0] += b[0]; v[1] += b[1]; v[2] += b[2]; v[3] += b[3];
  }
  if (MODE == 2){
    half4 h;
    #pragma unroll
    for (int j = 0; j < 4; j++){
      float g = 0.5f * v[j] * (1.f + erff(v[j] * 0.70710678118654752f));
      h[j] = (_Float16)g;
    }
    *(half4*)(outp + (size_t)row * N + col) = h;
  } else {
    *(floatx4*)(outf + (size_t)rowmap[row] * N + col) = v;
  }
}

// =======================================================================
// Unified per-layer weight convert: qkv/proj/gate/up/down in one dispatch.
// grid (54, 208). y-ranges: [0,60) qkv | [60,80) proj | [80,134) gate |
// [134,188) up | [188,208) down. WP plane layout (rows x Kpad):
//   qkv  rows [0,3840)        K=1280
//   proj rows [3840,5120)     K=1280
//   g/u  rows [5120,12032)    K=1280  (interleaved: gate 2n, up 2n+1)
//   down rows at elem 12032*1280, [0,1280) x K=3456
// =======================================================================
__global__ __launch_bounds__(256) void convert_layer_kernel(
    const float* __restrict__ qkv_w, const float* __restrict__ proj_w,
    const float* __restrict__ gate_w, const float* __restrict__ up_w,
    const float* __restrict__ down_w, _Float16* __restrict__ WP)
{
  const int bx = blockIdx.x, by = blockIdx.y;
  const float* Ws; int K, Nstride, n0, Kpad, rmul, radd; size_t dbase;
  if (by < 60){
    if (bx >= 20) return;
    Ws = qkv_w;  K = 1280; Nstride = 3840; n0 = by * 64;
    Kpad = 1280; dbase = 0; rmul = 1; radd = 0;
  } else if (by < 80){
    if (bx >= 20) return;
    Ws = proj_w; K = 1280; Nstride = 1280; n0 = (by - 60) * 64;
    Kpad = 1280; dbase = 3840ull * 1280; rmul = 1; radd = 0;
  } else if (by < 134){
    if (bx >= 20) return;
    Ws = gate_w; K = 1280; Nstride = 3456; n0 = (by - 80) * 64;
    Kpad = 1280; dbase = 5120ull * 1280; rmul = 2; radd = 0;
  } else if (by < 188){
    if (bx >= 20) return;
    Ws = up_w;   K = 1280; Nstride = 3456; n0 = (by - 134) * 64;
    Kpad = 1280; dbase = 5120ull * 1280; rmul = 2; radd = 1;
  } else {
    Ws = down_w; K = 3456; Nstride = 1280; n0 = (by - 188) * 64;
    Kpad = 3456; dbase = 12032ull * 1280; rmul = 1; radd = 0;
  }
  __shared__ float T[64][68];
  const int tid = threadIdx.x;
  const int k0 = bx * 64;
  const int kr = tid >> 4, nc = (tid & 15) << 2;
  #pragma unroll
  for (int p = 0; p < 4; p++){
    int k = k0 + p * 16 + kr;
    floatx4 v = *(const floatx4*)(Ws + (size_t)k * Nstride + n0 + nc);
    *(floatx4*)&T[p * 16 + kr][nc] = v;
  }
  __syncthreads();
  const int n = tid >> 2, kc = (tid & 3) << 4;
  half8 h0, h1;
  #pragma unroll
  for (int j = 0; j < 8; j++){
    h0[j] = (_Float16)T[kc + j][n];
    h1[j] = (_Float16)T[kc + 8 + j][n];
  }
  size_t ro = dbase + (size_t)((n0 + n) * rmul + radd) * Kpad + k0 + kc;
  *(half8*)&WP[ro] = h0; *(half8*)&WP[ro + 8] = h1;
}

// =======================================================================
// Standalone weight convert (patch / m1 / m2): W f32 [K][Nstride] ->
// transposed fp16 plane [N][Kpad], zero-pad k>=K.
// =======================================================================
__global__ __launch_bounds__(256) void convert_w_kernel(
    const float* __restrict__ W, _Float16* __restrict__ PH,
    int K, int Nstride, int Kpad)
{
  __shared__ float T[64][68];
  const int tid = threadIdx.x;
  const int k0 = blockIdx.x * 64, n0 = blockIdx.y * 64;
  const int kr = tid >> 4, nc = (tid & 15) << 2;
  #pragma unroll
  for (int p = 0; p < 4; p++){
    int k = k0 + p * 16 + kr;
    floatx4 v = {0.f, 0.f, 0.f, 0.f};
    if (k < K) v = *(const floatx4*)(W + (size_t)k * Nstride + n0 + nc);
    *(floatx4*)&T[p * 16 + kr][nc] = v;
  }
  __syncthreads();
  const int n = tid >> 2, kc = (tid & 3) << 4;
  half8 h0, h1;
  #pragma unroll
  for (int j = 0; j < 8; j++){
    h0[j] = (_Float16)T[kc + j][n];
    h1[j] = (_Float16)T[kc + 8 + j][n];
  }
  size_t ro = (size_t)(n0 + n) * Kpad + k0 + kc;
  *(half8*)&PH[ro] = h0; *(half8*)&PH[ro + 8] = h1;
}

// =======================================================================
// Patch gather (window perm folded) -> fp16 plane [1024][1216]
// =======================================================================
__global__ __launch_bounds__(256) void gather_x_kernel(
    const float* __restrict__ img, const int* __restrict__ win,
    _Float16* __restrict__ Xp)
{
  int idx = blockIdx.x * 256 + threadIdx.x;
  if (idx >= 1024 * 1216) return;
  int s = idx / 1216, f = idx - s * 1216;
  float val = 0.f;
  if (f < 1176){
    int sp = (win[s >> 2] << 2) | (s & 3);
    int i0 = sp >> 6, r = sp & 63;
    int i3 = r >> 2, rr = r & 3, i1 = rr >> 1, i4 = rr & 1;
    int c  = f / 392, f2 = f - c * 392;
    int f3 = f2 % 196;
    int ph = f3 / 14, pw2 = f3 - ph * 14;
    int hp = (i0 * 2 + i1) * 14 + ph, wp = (i3 * 2 + i4) * 14 + pw2;
    val = img[((size_t)c * 448 + hp) * 448 + wp];
  }
  Xp[idx] = (_Float16)val;
}

__global__ __launch_bounds__(256) void rope_tables_kernel(
    const float* __restrict__ rpe, const int* __restrict__ win,
    float* __restrict__ cosb, float* __restrict__ sinb)
{
  int idx = blockIdx.x * 256 + threadIdx.x;
  if (idx >= 1024 * 80) return;
  int s = idx / 80, d = idx - s * 80;
  int src = (win[s >> 2] << 2) | (s & 3);
  float ang = rpe[src * 40 + (d % 40)];
  cosb[idx] = cosf(ang);
  sinb[idx] = sinf(ang);
}

// =======================================================================
// Fused RoPE(Q,K) + V-transpose. QKV fp16 [1024][3840] ->
// Qp (pre-scaled) / Kp fp16 [16][1024][128] (d-pad 0), Vt fp16 [16][80][1024]
// =======================================================================
__global__ __launch_bounds__(256) void rope_vt_kernel(
    const _Float16* __restrict__ qkv,
    const float* __restrict__ cosb, const float* __restrict__ sinb,
    _Float16* __restrict__ Qp, _Float16* __restrict__ Kp,
    _Float16* __restrict__ Vt)
{
  __shared__ _Float16 T[64][81];
  const int h = blockIdx.y, s0 = blockIdx.x * 64;
  for (int c = threadIdx.x; c < 64 * 128; c += 256){
    int sl = c >> 7, d = c & 127;
    int s = s0 + sl;
    size_t o = ((size_t)h * 1024 + s) * 128 + d;
    if (d >= 80){ Qp[o] = (_Float16)0.f; Kp[o] = (_Float16)0.f; continue; }
    const _Float16* base = qkv + (size_t)s * 3840;
    float qv = (float)base[h * 80 + d], kv = (float)base[1280 + h * 80 + d];
    float qo = (d < 40) ? -(float)base[h * 80 + d + 40] : (float)base[h * 80 + d - 40];
    float ko = (d < 40) ? -(float)base[1280 + h * 80 + d + 40] : (float)base[1280 + h * 80 + d - 40];
    float cc = cosb[s * 80 + d], sn = sinb[s * 80 + d];
    Qp[o] = (_Float16)((qv * cc + qo * sn) * 0.11180339887498949f);
    Kp[o] = (_Float16)(kv * cc + ko * sn);
  }
  for (int c = threadIdx.x; c < 64 * 80; c += 256){
    int sl = c / 80, d = c - sl * 80;
    T[sl][d] = qkv[(size_t)(s0 + sl) * 3840 + 2560 + h * 80 + d];
  }
  __syncthreads();
  for (int c = threadIdx.x; c < 80 * 64; c += 256){
    int d = c >> 6, sl = c & 63;
    Vt[((size_t)h * 80 + d) * 1024 + s0 + sl] = T[sl][d];
  }
}

// concat gate_b/up_b interleaved -> [8][6912]
__global__ __launch_bounds__(256) void concat_bias_kernel(
    const float* __restrict__ gb, const float* __restrict__ ub, float* __restrict__ out)
{
  int idx = blockIdx.x * 256 + threadIdx.x;
  if (idx >= 8 * 6912) return;
  int l = idx / 6912, j = idx - l * 6912;
  out[idx] = (j & 1) ? ub[l * 3456 + (j >> 1)] : gb[l * 3456 + (j >> 1)];
}

// =======================================================================
// fp16 MFMA flash attention. block = (q-tile 64, head), 4 waves, KVBLK=32.
// =======================================================================
template<bool FULL>
__global__ __launch_bounds__(256) void attn_f16(
    const _Float16* __restrict__ Qp, const _Float16* __restrict__ Kp,
    const _Float16* __restrict__ Vt, _Float16* __restrict__ Op)
{
  __shared__ _Float16 KT[2][32 * 128];
  __shared__ _Float16 VS[2][80 * 32];
  __shared__ _Float16 PS[64 * 40];
  const int tid = threadIdx.x, lane = tid & 63, wv = tid >> 6;
  const int qb = blockIdx.x, h = blockIdx.y;
  const int fr = lane & 15, kg = lane >> 4;

  half8 qf[3];
  {
    size_t qbase = ((size_t)h * 1024 + qb * 64 + wv * 16 + fr) * 128;
    #pragma unroll
    for (int ks = 0; ks < 3; ks++)
      qf[ks] = *(const half8*)(Qp + qbase + ks * 32 + kg * 8);
  }
  float m_r[4], l_r[4];
  #pragma unroll
  for (int r = 0; r < 4; r++){ m_r[r] = -3e38f; l_r[r] = 0.f; }
  floatx4 oa[5];
  #pragma unroll
  for (int nb = 0; nb < 5; nb++) oa[nb] = 0.f;

  const int nt  = FULL ? 32 : 2;
  const int kt0 = FULL ? 0 : qb * 2;

  auto stageK = [&](int buf, int kt){
    #pragma unroll
    for (int p = 0; p < 2; p++){
      int lin = p * 256 + tid;
      int row = lin >> 4, gg = (lin & 15) ^ (row & 7);
      size_t go = ((size_t)h * 1024 + kt * 32 + row) * 128 + gg * 8;
      gld_lds16(Kp + go, &KT[buf][(p * 256 + wv * 64) * 8]);
    }
    #pragma unroll
    for (int p = 0; p < 2; p++){
      int lin = p * 256 + tid;
      if (lin < 320){
        int row = lin >> 2, gg = (lin & 3) ^ (row & 3);
        size_t go = ((size_t)h * 80 + row) * 1024 + kt * 32 + gg * 8;
        gld_lds16(Vt + go, &VS[buf][(p * 256 + wv * 64) * 8]);
      }
    }
  };

  stageK(0, kt0);
  __syncthreads();
  for (int t = 0; t < nt; t++){
    const int buf = t & 1;
    if (t + 1 < nt) stageK(buf ^ 1, kt0 + t + 1);
    floatx4 accS[2];
    accS[0] = 0.f; accS[1] = 0.f;
    #pragma unroll
    for (int c = 0; c < 2; c++){
      #pragma unroll
      for (int ks = 0; ks < 3; ks++){
        int row = c * 16 + fr;
        int off = row * 256 + ((ks * 64 + kg * 16) ^ ((row & 7) << 4));
        half8 kf = *(const half8*)((const char*)&KT[buf][0] + off);
        accS[c] = mfma_f16(qf[ks], kf, accS[c]);
      }
    }
    float corr[4], ps_[4];
    #pragma unroll
    for (int r = 0; r < 4; r++){
      float v = fmaxf(accS[0][r], accS[1][r]);
      v = fmaxf(v, __shfl_xor(v, 1)); v = fmaxf(v, __shfl_xor(v, 2));
      v = fmaxf(v, __shfl_xor(v, 4)); v = fmaxf(v, __shfl_xor(v, 8));
      float mn = fmaxf(m_r[r], v);
      corr[r] = __expf(m_r[r] - mn);
      m_r[r] = mn;
      ps_[r] = 0.f;
    }
    #pragma unroll
    for (int c = 0; c < 2; c++)
      #pragma unroll
      for (int r = 0; r < 4; r++){
        float p = __expf(accS[c][r] - m_r[r]);
        ps_[r] += p;
        PS[(wv * 16 + kg * 4 + r) * 40 + c * 16 + fr] = (_Float16)p;
      }
    #pragma unroll
    for (int r = 0; r < 4; r++){
      float v = ps_[r];
      v += __shfl_xor(v, 1); v += __shfl_xor(v, 2);
      v += __shfl_xor(v, 4); v += __shfl_xor(v, 8);
      l_r[r] = l_r[r] * corr[r] + v;
      #pragma unroll
      for (int nb = 0; nb < 5; nb++) oa[nb][r] *= corr[r];
    }
    {
      int poff = (wv * 16 + fr) * 80 + kg * 16;
      half8 pa = *(const half8*)((const char*)&PS[0] + poff);
      #pragma unroll
      for (int nb = 0; nb < 5; nb++){
        int row = nb * 16 + fr;
        int off = row * 64 + ((kg * 16) ^ ((row & 3) << 4));
        half8 vf = *(const half8*)((const char*)&VS[buf][0] + off);
        oa[nb] = mfma_f16(pa, vf, oa[nb]);
      }
    }
    __syncthreads();
  }
  float linv[4];
  #pragma unroll
  for (int r = 0; r < 4; r++) linv[r] = 1.f / l_r[r];
  #pragma unroll
  for (int nb = 0; nb < 5; nb++)
    #pragma unroll
    for (int r = 0; r < 4; r++){
      float v = oa[nb][r] * linv[r];
      size_t o = (size_t)(qb * 64 + wv * 16 + kg * 4 + r) * 1280 + h * 80 + nb * 16 + fr;
      Op[o] = (_Float16)v;
    }
}

// =======================================================================
extern "C" void kernel_launch(void* const* d_in, const int* in_sizes, int n_in,
                              void* d_out, int out_size, void* d_ws, size_t ws_size,
                              hipStream_t stream)
{
  (void)in_sizes; (void)n_in; (void)out_size;
  const float* images  = (const float*)d_in[0];
  const int*   win     = (const int*)  d_in[1];
  const float* rpe     = (const float*)d_in[3];
  const float* patch_w = (const float*)d_in[6];
  const float* ln1_w   = (const float*)d_in[7];
  const float* ln2_w   = (const float*)d_in[8];
  const float* qkv_w   = (const float*)d_in[9];
  const float* qkv_b   = (const float*)d_in[10];
  const float* proj_w  = (const float*)d_in[11];
  const float* proj_b  = (const float*)d_in[12];
  const float* gate_w  = (const float*)d_in[13];
  const float* gate_b  = (const float*)d_in[14];
  const float* up_w    = (const float*)d_in[15];
  const float* up_b    = (const float*)d_in[16];
  const float* down_w  = (const float*)d_in[17];
  const float* down_b  = (const float*)d_in[18];
  const float* lnq_w   = (const float*)d_in[19];
  const float* m1_w    = (const float*)d_in[20];
  const float* m1_b    = (const float*)d_in[21];
  const float* m2_w    = (const float*)d_in[22];
  const float* m2_b    = (const float*)d_in[23];

  char* ws = (char*)d_ws;
  size_t off = 0;
  auto alloc = [&](size_t b){ size_t o = off; off += (b + 255) & ~(size_t)255; return o; };
  _Float16* WP  = (_Float16*)(ws + alloc(26214400ull * 2));   // 52.4MB
  float* PART = (float*)(ws + alloc(22020096ull));            // 21MB
  _Float16* Xp  = (_Float16*)(ws + alloc(1024ull * 1216 * 2));
  _Float16* ANp = (_Float16*)(ws + alloc(1024ull * 1280 * 2));
  float* H    = (float*)(ws + alloc(1024ull * 1280 * 4));
  _Float16* QKVh = (_Float16*)(ws + alloc(1024ull * 3840 * 2));
  _Float16* Qp = (_Float16*)(ws + alloc(16ull * 1024 * 128 * 2));
  _Float16* Kp = (_Float16*)(ws + alloc(16ull * 1024 * 128 * 2));
  _Float16* Vt = (_Float16*)(ws + alloc(16ull * 80 * 1024 * 2));
  _Float16* Op  = (_Float16*)(ws + alloc(1024ull * 1280 * 2));
  _Float16* DAp = (_Float16*)(ws + alloc(1024ull * 3456 * 2));
  _Float16* G1p = (_Float16*)(ws + alloc(256ull * 5120 * 2));
  float* COSb = (float*)(ws + alloc(1024ull * 80 * 4));
  float* SINb = (float*)(ws + alloc(1024ull * 80 * 4));
  float* BGU  = (float*)(ws + alloc(8ull * 6912 * 4));
  if (off > ws_size) return;

  const _Float16* WPqkv  = WP;
  const _Float16* WPproj = WP + 3840ull * 1280;
  const _Float16* WPgu   = WP + 5120ull * 1280;
  const _Float16* WPdown = WP + 12032ull * 1280;

  gather_x_kernel   <<<4864, 256, 0, stream>>>(images, win, Xp);
  rope_tables_kernel<<<320,  256, 0, stream>>>(rpe, win, COSb, SINb);
  concat_bias_kernel<<<216,  256, 0, stream>>>(gate_b, up_b, BGU);

  // patch embed: split-K2 (320 blocks) -> fused reduce + ln1(0)
  convert_w_kernel<<<dim3(19, 20), 256, 0, stream>>>(patch_w, WP, 1176, 1280, 1216);
  gemm_f16<0, 2><<<dim3(10, 16, 2), 128, 0, stream>>>(
      Xp, WP, nullptr, nullptr, nullptr, 1216, 1280, 1024, PART);
  reduce_rms<<<1024, 256, 0, stream>>>(PART, 2, nullptr, nullptr, H, ln1_w, ANp);

  for (int i = 0; i < 8; i++){
    // one unified convert for all 4 weight matrices of this layer
    convert_layer_kernel<<<dim3(54, 208), 256, 0, stream>>>(
        qkv_w + (size_t)i * 1280 * 3840, proj_w + (size_t)i * 1280 * 1280,
        gate_w + (size_t)i * 1280 * 3456, up_w + (size_t)i * 1280 * 3456,
        down_w + (size_t)i * 3456 * 1280, WP);
    // qkv: 480 blocks, bias fused, fp16 out
    gemm_f16<5, 1><<<dim3(30, 16), 128, 0, stream>>>(
        ANp, WPqkv, qkv_b + (size_t)i * 3840, nullptr, QKVh, 1280, 3840, 1024, nullptr);
    rope_vt_kernel<<<dim3(16, 16), 256, 0, stream>>>(QKVh, COSb, SINb, Qp, Kp, Vt);
    if (i == 3 || i == 7)
      attn_f16<true ><<<dim3(16, 16), 256, 0, stream>>>(Qp, Kp, Vt, Op);
    else
      attn_f16<false><<<dim3(16, 16), 256, 0, stream>>>(Qp, Kp, Vt, Op);
    // proj: split-K2 (320 blocks) -> fused reduce(+bias+res) + ln2
    gemm_f16<0, 2><<<dim3(10, 16, 2), 128, 0, stream>>>(
        Op, WPproj, nullptr, nullptr, nullptr, 1280, 1280, 1024, PART);
    reduce_rms<<<1024, 256, 0, stream>>>(PART, 2,
        proj_b + (size_t)i * 1280, H, H, ln2_w + (size_t)i * 1280, ANp);
    // fused gate+up (interleaved): 864 blocks, silu epilogue
    gemm_f16<4, 1><<<dim3(54, 16), 128, 0, stream>>>(
        ANp, WPgu, BGU + (size_t)i * 6912, nullptr, DAp, 1280, 6912, 1024, nullptr);
    // down: split-K2 (320 blocks) -> fused reduce(+bias+res) + ln1(i+1)/lnq
    gemm_f16<0, 2><<<dim3(10, 16, 2), 128, 0, stream>>>(
        DAp, WPdown, nullptr, nullptr, nullptr, 3456, 1280, 1024, PART);
    const float* next_w = (i == 7) ? lnq_w : (ln1_w + (size_t)(i + 1) * 1280);
    reduce_rms<<<1024, 256, 0, stream>>>(PART, 2,
        down_b + (size_t)i * 1280, H, H, next_w, ANp);
  }

  // merger
  // m1: 256x5120x5120, split-K4 (640 blocks), gelu -> fp16 plane
  convert_w_kernel<<<dim3(80, 80), 256, 0, stream>>>(m1_w, WP, 5120, 5120, 5120);
  gemm_f16<0, 4><<<dim3(40, 4, 4), 128, 0, stream>>>(
      ANp, WP, nullptr, nullptr, nullptr, 5120, 5120, 256, PART);
  reduce_k<2><<<1280, 256, 0, stream>>>(PART, 4, 256, 5120, m1_b, nullptr, G1p, nullptr);
  // m2: 256x3584x5120, split-K4 (448 blocks), scatter rows
  convert_w_kernel<<<dim3(80, 56), 256, 0, stream>>>(m2_w, WP, 5120, 3584, 5120);
  gemm_f16<0, 4><<<dim3(28, 4, 4), 128, 0, stream>>>(
      G1p, WP, nullptr, nullptr, nullptr, 5120, 3584, 256, PART);
  reduce_k<3><<<896, 256, 0, stream>>>(PART, 4, 256, 3584, m2_b, (float*)d_out, nullptr, win);
}

// Round 10
// 1541.962 us; speedup vs baseline: 1.2164x; 1.2164x over previous
//
#include <hip/hip_runtime.h>
#include <math.h>

typedef float  floatx4  __attribute__((ext_vector_type(4)));
typedef _Float16 half8  __attribute__((ext_vector_type(8)));
typedef _Float16 half4  __attribute__((ext_vector_type(4)));

// ---------- MFMA 16x16x32 f16 ----------
// A-frag: lane l holds A[l&15][(l>>4)*8+j]; B-frag: lane l holds B[(l>>4)*8+j][l&15]
// C/D: lane l reg r = D[(l>>4)*4+r][l&15]   (verified rounds 1-9)
__device__ inline floatx4 mfma_f16(half8 a, half8 b, floatx4 c){
  return __builtin_amdgcn_mfma_f32_16x16x32_f16(a, b, c, 0, 0, 0);
}

// ---------- async global->LDS, 16B per lane ----------
__device__ inline void gld_lds16(const void* g, void* l){
  __builtin_amdgcn_global_load_lds(
      (const __attribute__((address_space(1))) unsigned int*)g,
      (__attribute__((address_space(3))) unsigned int*)l, 16, 0, 0);
}

// =======================================================================
// fp16 GEMM, 256 threads (4 waves 2x2), tile 64x128, wave-tile 32x64.
// BK = K-step (32 or 64). BK=64 halves barrier count; LDS 48KB -> 3/CU.
// Double-buffered LDS, gld_lds staging, granule-XOR swizzle, XCD swizzle.
// KSPLIT>1 -> f32 partials. Modes: 0 outf=acc+bias; 4 gate/up silu->fp16.
// =======================================================================
template<int MODE, int KSPLIT, int BK>
__global__ __launch_bounds__(256) void gemm_f16(
    const _Float16* __restrict__ A, const _Float16* __restrict__ W,
    const float* __restrict__ bias,
    float* __restrict__ outf, _Float16* __restrict__ outp,
    int K, int Nout, int Mtot, float* __restrict__ part)
{
  constexpr int BM = 64, BN = 128, GPR = BK / 8;
  __shared__ _Float16 SA[2][BM*BK];
  __shared__ _Float16 SW[2][BN*BK];
  const int tid = threadIdx.x, lane = tid & 63, wv = tid >> 6;
  const int wm = wv >> 1, wn = wv & 1;

  int m_idx, n_idx;
  {
    const int gx = gridDim.x, gy = gridDim.y;
    const int T = gx * gy;
    int id = blockIdx.y * gx + blockIdx.x;
    if ((T & 7) == 0){
      int wg = (id & 7) * (T >> 3) + (id >> 3);
      n_idx = wg / gy; m_idx = wg - n_idx * gy;
    } else { n_idx = blockIdx.x; m_idx = blockIdx.y; }
  }
  const int m0 = m_idx * BM, n0 = n_idx * BN;
  const int kbase = (KSPLIT > 1) ? blockIdx.z * (K / KSPLIT) : 0;
  floatx4 acc[2][4];
  #pragma unroll
  for (int mr = 0; mr < 2; mr++)
    #pragma unroll
    for (int nr = 0; nr < 4; nr++) acc[mr][nr] = 0.f;
  const int fr = lane & 15, kg = lane >> 4;

  auto stage = [&](int buf, int k0){
    #pragma unroll
    for (int p = 0; p < (BM * GPR) / 256; p++){
      int lin = p * 256 + tid;
      int row = lin / GPR, gi = lin % GPR;
      int gg = (BK == 64) ? (gi ^ (row & 7)) : (gi ^ ((row >> 1) & 3));
      size_t go = (size_t)(m0 + row) * K + kbase + k0 + gg * 8;
      gld_lds16(A + go, &SA[buf][(p * 256 + wv * 64) * 8]);
    }
    #pragma unroll
    for (int p = 0; p < (BN * GPR) / 256; p++){
      int lin = p * 256 + tid;
      int row = lin / GPR, gi = lin % GPR;
      int gg = (BK == 64) ? (gi ^ (row & 7)) : (gi ^ ((row >> 1) & 3));
      size_t go = (size_t)(n0 + row) * K + kbase + k0 + gg * 8;
      gld_lds16(W + go, &SW[buf][(p * 256 + wv * 64) * 8]);
    }
  };

  stage(0, 0);
  __syncthreads();
  const int nt = (K / KSPLIT) / BK;
  for (int t = 0; t < nt; t++){
    const int buf = t & 1;
    if (t + 1 < nt) stage(buf ^ 1, (t + 1) * BK);
    #pragma unroll
    for (int ks = 0; ks < BK / 32; ks++){
      half8 af[2], wf[4];
      #pragma unroll
      for (int mr = 0; mr < 2; mr++){
        int r = wm * 32 + mr * 16 + fr;
        int off = (BK == 64) ? r * 128 + (((ks * 4 + kg) ^ (r & 7)) << 4)
                             : r * 64  + ((kg ^ ((r >> 1) & 3)) << 4);
        af[mr] = *(const half8*)((const char*)&SA[buf][0] + off);
      }
      #pragma unroll
      for (int nr = 0; nr < 4; nr++){
        int r = wn * 64 + nr * 16 + fr;
        int off = (BK == 64) ? r * 128 + (((ks * 4 + kg) ^ (r & 7)) << 4)
                             : r * 64  + ((kg ^ ((r >> 1) & 3)) << 4);
        wf[nr] = *(const half8*)((const char*)&SW[buf][0] + off);
      }
      #pragma unroll
      for (int mr = 0; mr < 2; mr++)
        #pragma unroll
        for (int nr = 0; nr < 4; nr++)
          acc[mr][nr] = mfma_f16(af[mr], wf[nr], acc[mr][nr]);
    }
    __syncthreads();
  }
  #pragma unroll
  for (int mr = 0; mr < 2; mr++)
    #pragma unroll
    for (int nr = 0; nr < 4; nr++){
      int np = n0 + wn * 64 + nr * 16 + fr;
      #pragma unroll
      for (int e = 0; e < 4; e++){
        int row = m0 + wm * 32 + mr * 16 + kg * 4 + e;
        float v = acc[mr][nr][e];
        if (KSPLIT > 1){
          part[((size_t)blockIdx.z * Mtot + row) * Nout + np] = v;
        } else {
          v += bias ? bias[np] : 0.f;
          if (MODE == 0) outf[(size_t)row * Nout + np] = v;
          if (MODE == 4){
            float pv = __shfl_xor(v, 1);
            if (!(fr & 1)){
              float dv = v / (1.f + __expf(-v)) * pv;
              outp[(size_t)row * (Nout >> 1) + (np >> 1)] = (_Float16)dv;
            }
          }
        }
      }
    }
}

// =======================================================================
// Fused split-K reduce (+bias +res) -> H (f32) -> RMSNorm -> fp16 plane.
// One block per row; M=1024, N=1280 fixed.
// =======================================================================
__global__ __launch_bounds__(256) void reduce_rms(
    const float* __restrict__ part, int Z,
    const float* __restrict__ bias, const float* __restrict__ res,
    float* __restrict__ Hout, const float* __restrict__ w,
    _Float16* __restrict__ ANp)
{
  const int row = blockIdx.x;
  float v[5];
  float ss = 0.f;
  #pragma unroll
  for (int j = 0; j < 5; j++){
    int col = threadIdx.x + j * 256;
    float t = part[(size_t)row * 1280 + col];
    for (int z = 1; z < Z; z++)
      t += part[((size_t)z * 1024 + row) * 1280 + col];
    if (bias) t += bias[col];
    if (res)  t += res[(size_t)row * 1280 + col];
    v[j] = t;
    Hout[(size_t)row * 1280 + col] = t;
    ss = fmaf(t, t, ss);
  }
  for (int o = 32; o > 0; o >>= 1) ss += __shfl_down(ss, o);
  __shared__ float wsum[4];
  __shared__ float snorm;
  if ((threadIdx.x & 63) == 0) wsum[threadIdx.x >> 6] = ss;
  __syncthreads();
  if (threadIdx.x == 0){
    float t = wsum[0] + wsum[1] + wsum[2] + wsum[3];
    snorm = 1.0f / sqrtf(t * (1.0f / 1280.0f) + 1e-6f);
  }
  __syncthreads();
  float s = snorm;
  #pragma unroll
  for (int j = 0; j < 5; j++){
    int col = threadIdx.x + j * 256;
    ANp[(size_t)row * 1280 + col] = (_Float16)(v[j] * s * w[col]);
  }
}

// =======================================================================
// Generic split-K reduce + epilogue (merger). part[z][M][N] f32.
// MODE 2: outp(fp16) = gelu_exact(sum + bias)
// MODE 3: outf[rowmap[row]*N + col] = sum + bias
// =======================================================================
template<int MODE>
__global__ __launch_bounds__(256) void reduce_k(
    const float* __restrict__ part, int Z, int M, int N,
    const float* __restrict__ bias,
    float* __restrict__ outf, _Float16* __restrict__ outp,
    const int* __restrict__ rowmap)
{
  int idx4 = (blockIdx.x * 256 + threadIdx.x) * 4;
  if (idx4 >= M * N) return;
  int row = idx4 / N, col = idx4 - row * N;
  floatx4 v = *(const floatx4*)(part + (size_t)row * N + col);
  for (int z = 1; z < Z; z++){
    floatx4 p = *(const floatx4*)(part + ((size_t)z * M + row) * N + col);
    v[0] += p[0]; v[1] += p[1]; v[2] += p[2]; v[3] += p[3];
  }
  if (bias){
    floatx4 b = *(const floatx4*)(bias + col);
    v[0] += b[0]; v[1] += b[1]; v[2] += b[2]; v[3] += b[3];
  }
  if (MODE == 2){
    half4 h;
    #pragma unroll
    for (int j = 0; j < 4; j++){
      float g = 0.5f * v[j] * (1.f + erff(v[j] * 0.70710678118654752f));
      h[j] = (_Float16)g;
    }
    *(half4*)(outp + (size_t)row * N + col) = h;
  } else {
    *(floatx4*)(outf + (size_t)rowmap[row] * N + col) = v;
  }
}

// =======================================================================
// Unified per-layer weight convert, tight 1-D grid (4840 blocks).
// Segments: [0,1200) qkv 20x60 | [1200,1600) proj 20x20 |
// [1600,2680) gate 20x54 | [2680,3760) up 20x54 | [3760,4840) down 54x20.
// WP layout (rows x Kpad): qkv [0,3840) K1280 | proj [3840,5120) K1280 |
// g/u interleaved [5120,12032) K1280 | down at elem 12032*1280, 1280 x K3456.
// =======================================================================
__global__ __launch_bounds__(256) void convert_layer_kernel(
    const float* __restrict__ qkv_w, const float* __restrict__ proj_w,
    const float* __restrict__ gate_w, const float* __restrict__ up_w,
    const float* __restrict__ down_w, _Float16* __restrict__ WP)
{
  const int bid = blockIdx.x;
  const float* Ws; int Nstride, n0, Kpad, rmul, radd, kb; size_t dbase;
  if (bid < 1200){
    int l = bid; kb = l % 20; int nb = l / 20;
    Ws = qkv_w;  Nstride = 3840; n0 = nb * 64; Kpad = 1280;
    dbase = 0; rmul = 1; radd = 0;
  } else if (bid < 1600){
    int l = bid - 1200; kb = l % 20; int nb = l / 20;
    Ws = proj_w; Nstride = 1280; n0 = nb * 64; Kpad = 1280;
    dbase = 3840ull * 1280; rmul = 1; radd = 0;
  } else if (bid < 2680){
    int l = bid - 1600; kb = l % 20; int nb = l / 20;
    Ws = gate_w; Nstride = 3456; n0 = nb * 64; Kpad = 1280;
    dbase = 5120ull * 1280; rmul = 2; radd = 0;
  } else if (bid < 3760){
    int l = bid - 2680; kb = l % 20; int nb = l / 20;
    Ws = up_w;   Nstride = 3456; n0 = nb * 64; Kpad = 1280;
    dbase = 5120ull * 1280; rmul = 2; radd = 1;
  } else {
    int l = bid - 3760; kb = l % 54; int nb = l / 54;
    Ws = down_w; Nstride = 1280; n0 = nb * 64; Kpad = 3456;
    dbase = 12032ull * 1280; rmul = 1; radd = 0;
  }
  __shared__ float T[64][68];
  const int tid = threadIdx.x;
  const int k0 = kb * 64;
  const int kr = tid >> 4, nc = (tid & 15) << 2;
  #pragma unroll
  for (int p = 0; p < 4; p++){
    int k = k0 + p * 16 + kr;
    floatx4 v = *(const floatx4*)(Ws + (size_t)k * Nstride + n0 + nc);
    *(floatx4*)&T[p * 16 + kr][nc] = v;
  }
  __syncthreads();
  const int n = tid >> 2, kc = (tid & 3) << 4;
  half8 h0, h1;
  #pragma unroll
  for (int j = 0; j < 8; j++){
    h0[j] = (_Float16)T[kc + j][n];
    h1[j] = (_Float16)T[kc + 8 + j][n];
  }
  size_t ro = dbase + (size_t)((n0 + n) * rmul + radd) * Kpad + k0 + kc;
  *(half8*)&WP[ro] = h0; *(half8*)&WP[ro + 8] = h1;
}

// =======================================================================
// Standalone weight convert (patch / m1 / m2): W f32 [K][Nstride] ->
// transposed fp16 plane [N][Kpad], zero-pad k>=K.
// =======================================================================
__global__ __launch_bounds__(256) void convert_w_kernel(
    const float* __restrict__ W, _Float16* __restrict__ PH,
    int K, int Nstride, int Kpad)
{
  __shared__ float T[64][68];
  const int tid = threadIdx.x;
  const int k0 = blockIdx.x * 64, n0 = blockIdx.y * 64;
  const int kr = tid >> 4, nc = (tid & 15) << 2;
  #pragma unroll
  for (int p = 0; p < 4; p++){
    int k = k0 + p * 16 + kr;
    floatx4 v = {0.f, 0.f, 0.f, 0.f};
    if (k < K) v = *(const floatx4*)(W + (size_t)k * Nstride + n0 + nc);
    *(floatx4*)&T[p * 16 + kr][nc] = v;
  }
  __syncthreads();
  const int n = tid >> 2, kc = (tid & 3) << 4;
  half8 h0, h1;
  #pragma unroll
  for (int j = 0; j < 8; j++){
    h0[j] = (_Float16)T[kc + j][n];
    h1[j] = (_Float16)T[kc + 8 + j][n];
  }
  size_t ro = (size_t)(n0 + n) * Kpad + k0 + kc;
  *(half8*)&PH[ro] = h0; *(half8*)&PH[ro + 8] = h1;
}

// =======================================================================
// Patch gather (window perm folded) -> fp16 plane [1024][1280] (zero-pad)
// =======================================================================
__global__ __launch_bounds__(256) void gather_x_kernel(
    const float* __restrict__ img, const int* __restrict__ win,
    _Float16* __restrict__ Xp)
{
  int idx = blockIdx.x * 256 + threadIdx.x;
  if (idx >= 1024 * 1280) return;
  int s = idx / 1280, f = idx - s * 1280;
  float val = 0.f;
  if (f < 1176){
    int sp = (win[s >> 2] << 2) | (s & 3);
    int i0 = sp >> 6, r = sp & 63;
    int i3 = r >> 2, rr = r & 3, i1 = rr >> 1, i4 = rr & 1;
    int c  = f / 392, f2 = f - c * 392;
    int f3 = f2 % 196;
    int ph = f3 / 14, pw2 = f3 - ph * 14;
    int hp = (i0 * 2 + i1) * 14 + ph, wp = (i3 * 2 + i4) * 14 + pw2;
    val = img[((size_t)c * 448 + hp) * 448 + wp];
  }
  Xp[idx] = (_Float16)val;
}

__global__ __launch_bounds__(256) void rope_tables_kernel(
    const float* __restrict__ rpe, const int* __restrict__ win,
    float* __restrict__ cosb, float* __restrict__ sinb)
{
  int idx = blockIdx.x * 256 + threadIdx.x;
  if (idx >= 1024 * 80) return;
  int s = idx / 80, d = idx - s * 80;
  int src = (win[s >> 2] << 2) | (s & 3);
  float ang = rpe[src * 40 + (d % 40)];
  cosb[idx] = cosf(ang);
  sinb[idx] = sinf(ang);
}

// =======================================================================
// Fused RoPE(Q,K) + V-transpose. QKV f32 [1024][3840] ->
// Qp (pre-scaled) / Kp fp16 [16][1024][128] (d-pad 0), Vt fp16 [16][80][1024]
// =======================================================================
__global__ __launch_bounds__(256) void rope_vt_kernel(
    const float* __restrict__ qkv,
    const float* __restrict__ cosb, const float* __restrict__ sinb,
    _Float16* __restrict__ Qp, _Float16* __restrict__ Kp,
    _Float16* __restrict__ Vt)
{
  __shared__ _Float16 T[64][81];
  const int h = blockIdx.y, s0 = blockIdx.x * 64;
  for (int c = threadIdx.x; c < 64 * 128; c += 256){
    int sl = c >> 7, d = c & 127;
    int s = s0 + sl;
    size_t o = ((size_t)h * 1024 + s) * 128 + d;
    if (d >= 80){ Qp[o] = (_Float16)0.f; Kp[o] = (_Float16)0.f; continue; }
    const float* base = qkv + (size_t)s * 3840;
    float qv = base[h * 80 + d], kv = base[1280 + h * 80 + d];
    float qo = (d < 40) ? -base[h * 80 + d + 40] : base[h * 80 + d - 40];
    float ko = (d < 40) ? -base[1280 + h * 80 + d + 40] : base[1280 + h * 80 + d - 40];
    float cc = cosb[s * 80 + d], sn = sinb[s * 80 + d];
    Qp[o] = (_Float16)((qv * cc + qo * sn) * 0.11180339887498949f);
    Kp[o] = (_Float16)(kv * cc + ko * sn);
  }
  for (int c = threadIdx.x; c < 64 * 80; c += 256){
    int sl = c / 80, d = c - sl * 80;
    T[sl][d] = (_Float16)qkv[(size_t)(s0 + sl) * 3840 + 2560 + h * 80 + d];
  }
  __syncthreads();
  for (int c = threadIdx.x; c < 80 * 64; c += 256){
    int d = c >> 6, sl = c & 63;
    Vt[((size_t)h * 80 + d) * 1024 + s0 + sl] = T[sl][d];
  }
}

// concat gate_b/up_b interleaved -> [8][6912]
__global__ __launch_bounds__(256) void concat_bias_kernel(
    const float* __restrict__ gb, const float* __restrict__ ub, float* __restrict__ out)
{
  int idx = blockIdx.x * 256 + threadIdx.x;
  if (idx >= 8 * 6912) return;
  int l = idx / 6912, j = idx - l * 6912;
  out[idx] = (j & 1) ? ub[l * 3456 + (j >> 1)] : gb[l * 3456 + (j >> 1)];
}

// =======================================================================
// fp16 MFMA flash attention. block = (q-tile 64, head), 4 waves, KVBLK=32.
// =======================================================================
template<bool FULL>
__global__ __launch_bounds__(256) void attn_f16(
    const _Float16* __restrict__ Qp, const _Float16* __restrict__ Kp,
    const _Float16* __restrict__ Vt, _Float16* __restrict__ Op)
{
  __shared__ _Float16 KT[2][32 * 128];
  __shared__ _Float16 VS[2][80 * 32];
  __shared__ _Float16 PS[64 * 40];
  const int tid = threadIdx.x, lane = tid & 63, wv = tid >> 6;
  const int qb = blockIdx.x, h = blockIdx.y;
  const int fr = lane & 15, kg = lane >> 4;

  half8 qf[3];
  {
    size_t qbase = ((size_t)h * 1024 + qb * 64 + wv * 16 + fr) * 128;
    #pragma unroll
    for (int ks = 0; ks < 3; ks++)
      qf[ks] = *(const half8*)(Qp + qbase + ks * 32 + kg * 8);
  }
  float m_r[4], l_r[4];
  #pragma unroll
  for (int r = 0; r < 4; r++){ m_r[r] = -3e38f; l_r[r] = 0.f; }
  floatx4 oa[5];
  #pragma unroll
  for (int nb = 0; nb < 5; nb++) oa[nb] = 0.f;

  const int nt  = FULL ? 32 : 2;
  const int kt0 = FULL ? 0 : qb * 2;

  auto stageK = [&](int buf, int kt){
    #pragma unroll
    for (int p = 0; p < 2; p++){
      int lin = p * 256 + tid;
      int row = lin >> 4, gg = (lin & 15) ^ (row & 7);
      size_t go = ((size_t)h * 1024 + kt * 32 + row) * 128 + gg * 8;
      gld_lds16(Kp + go, &KT[buf][(p * 256 + wv * 64) * 8]);
    }
    #pragma unroll
    for (int p = 0; p < 2; p++){
      int lin = p * 256 + tid;
      if (lin < 320){
        int row = lin >> 2, gg = (lin & 3) ^ (row & 3);
        size_t go = ((size_t)h * 80 + row) * 1024 + kt * 32 + gg * 8;
        gld_lds16(Vt + go, &VS[buf][(p * 256 + wv * 64) * 8]);
      }
    }
  };

  stageK(0, kt0);
  __syncthreads();
  for (int t = 0; t < nt; t++){
    const int buf = t & 1;
    if (t + 1 < nt) stageK(buf ^ 1, kt0 + t + 1);
    floatx4 accS[2];
    accS[0] = 0.f; accS[1] = 0.f;
    #pragma unroll
    for (int c = 0; c < 2; c++){
      #pragma unroll
      for (int ks = 0; ks < 3; ks++){
        int row = c * 16 + fr;
        int off = row * 256 + ((ks * 64 + kg * 16) ^ ((row & 7) << 4));
        half8 kf = *(const half8*)((const char*)&KT[buf][0] + off);
        accS[c] = mfma_f16(qf[ks], kf, accS[c]);
      }
    }
    float corr[4], ps_[4];
    #pragma unroll
    for (int r = 0; r < 4; r++){
      float v = fmaxf(accS[0][r], accS[1][r]);
      v = fmaxf(v, __shfl_xor(v, 1)); v = fmaxf(v, __shfl_xor(v, 2));
      v = fmaxf(v, __shfl_xor(v, 4)); v = fmaxf(v, __shfl_xor(v, 8));
      float mn = fmaxf(m_r[r], v);
      corr[r] = __expf(m_r[r] - mn);
      m_r[r] = mn;
      ps_[r] = 0.f;
    }
    #pragma unroll
    for (int c = 0; c < 2; c++)
      #pragma unroll
      for (int r = 0; r < 4; r++){
        float p = __expf(accS[c][r] - m_r[r]);
        ps_[r] += p;
        PS[(wv * 16 + kg * 4 + r) * 40 + c * 16 + fr] = (_Float16)p;
      }
    #pragma unroll
    for (int r = 0; r < 4; r++){
      float v = ps_[r];
      v += __shfl_xor(v, 1); v += __shfl_xor(v, 2);
      v += __shfl_xor(v, 4); v += __shfl_xor(v, 8);
      l_r[r] = l_r[r] * corr[r] + v;
      #pragma unroll
      for (int nb = 0; nb < 5; nb++) oa[nb][r] *= corr[r];
    }
    {
      int poff = (wv * 16 + fr) * 80 + kg * 16;
      half8 pa = *(const half8*)((const char*)&PS[0] + poff);
      #pragma unroll
      for (int nb = 0; nb < 5; nb++){
        int row = nb * 16 + fr;
        int off = row * 64 + ((kg * 16) ^ ((row & 3) << 4));
        half8 vf = *(const half8*)((const char*)&VS[buf][0] + off);
        oa[nb] = mfma_f16(pa, vf, oa[nb]);
      }
    }
    __syncthreads();
  }
  float linv[4];
  #pragma unroll
  for (int r = 0; r < 4; r++) linv[r] = 1.f / l_r[r];
  #pragma unroll
  for (int nb = 0; nb < 5; nb++)
    #pragma unroll
    for (int r = 0; r < 4; r++){
      float v = oa[nb][r] * linv[r];
      size_t o = (size_t)(qb * 64 + wv * 16 + kg * 4 + r) * 1280 + h * 80 + nb * 16 + fr;
      Op[o] = (_Float16)v;
    }
}

// =======================================================================
extern "C" void kernel_launch(void* const* d_in, const int* in_sizes, int n_in,
                              void* d_out, int out_size, void* d_ws, size_t ws_size,
                              hipStream_t stream)
{
  (void)in_sizes; (void)n_in; (void)out_size;
  const float* images  = (const float*)d_in[0];
  const int*   win     = (const int*)  d_in[1];
  const float* rpe     = (const float*)d_in[3];
  const float* patch_w = (const float*)d_in[6];
  const float* ln1_w   = (const float*)d_in[7];
  const float* ln2_w   = (const float*)d_in[8];
  const float* qkv_w   = (const float*)d_in[9];
  const float* qkv_b   = (const float*)d_in[10];
  const float* proj_w  = (const float*)d_in[11];
  const float* proj_b  = (const float*)d_in[12];
  const float* gate_w  = (const float*)d_in[13];
  const float* gate_b  = (const float*)d_in[14];
  const float* up_w    = (const float*)d_in[15];
  const float* up_b    = (const float*)d_in[16];
  const float* down_w  = (const float*)d_in[17];
  const float* down_b  = (const float*)d_in[18];
  const float* lnq_w   = (const float*)d_in[19];
  const float* m1_w    = (const float*)d_in[20];
  const float* m1_b    = (const float*)d_in[21];
  const float* m2_w    = (const float*)d_in[22];
  const float* m2_b    = (const float*)d_in[23];

  char* ws = (char*)d_ws;
  size_t off = 0;
  auto alloc = [&](size_t b){ size_t o = off; off += (b + 255) & ~(size_t)255; return o; };
  _Float16* WP  = (_Float16*)(ws + alloc(26214400ull * 2));   // 52.4MB
  float* PART = (float*)(ws + alloc(22020096ull));            // 21MB
  _Float16* Xp  = (_Float16*)(ws + alloc(1024ull * 1280 * 2));
  _Float16* ANp = (_Float16*)(ws + alloc(1024ull * 1280 * 2));
  float* H    = (float*)(ws + alloc(1024ull * 1280 * 4));
  float* QKV  = (float*)(ws + alloc(1024ull * 3840 * 4));
  _Float16* Qp = (_Float16*)(ws + alloc(16ull * 1024 * 128 * 2));
  _Float16* Kp = (_Float16*)(ws + alloc(16ull * 1024 * 128 * 2));
  _Float16* Vt = (_Float16*)(ws + alloc(16ull * 80 * 1024 * 2));
  _Float16* Op  = (_Float16*)(ws + alloc(1024ull * 1280 * 2));
  _Float16* DAp = (_Float16*)(ws + alloc(1024ull * 3456 * 2));
  _Float16* G1p = (_Float16*)(ws + alloc(256ull * 5120 * 2));
  float* COSb = (float*)(ws + alloc(1024ull * 80 * 4));
  float* SINb = (float*)(ws + alloc(1024ull * 80 * 4));
  float* BGU  = (float*)(ws + alloc(8ull * 6912 * 4));
  if (off > ws_size) return;

  const _Float16* WPqkv  = WP;
  const _Float16* WPproj = WP + 3840ull * 1280;
  const _Float16* WPgu   = WP + 5120ull * 1280;
  const _Float16* WPdown = WP + 12032ull * 1280;

  gather_x_kernel   <<<5120, 256, 0, stream>>>(images, win, Xp);
  rope_tables_kernel<<<320,  256, 0, stream>>>(rpe, win, COSb, SINb);
  concat_bias_kernel<<<216,  256, 0, stream>>>(gate_b, up_b, BGU);

  // patch embed: Kpad 1280, split-K2 (320 blocks) -> fused reduce + ln1(0)
  convert_w_kernel<<<dim3(20, 20), 256, 0, stream>>>(patch_w, WP, 1176, 1280, 1280);
  gemm_f16<0, 2, 64><<<dim3(10, 16, 2), 256, 0, stream>>>(
      Xp, WP, nullptr, nullptr, nullptr, 1280, 1280, 1024, PART);
  reduce_rms<<<1024, 256, 0, stream>>>(PART, 2, nullptr, nullptr, H, ln1_w, ANp);

  for (int i = 0; i < 8; i++){
    // one tight unified convert for all 4 weight matrices of this layer
    convert_layer_kernel<<<4840, 256, 0, stream>>>(
        qkv_w + (size_t)i * 1280 * 3840, proj_w + (size_t)i * 1280 * 1280,
        gate_w + (size_t)i * 1280 * 3456, up_w + (size_t)i * 1280 * 3456,
        down_w + (size_t)i * 3456 * 1280, WP);
    // qkv: 480 blocks, bias fused, f32 out
    gemm_f16<0, 1, 64><<<dim3(30, 16), 256, 0, stream>>>(
        ANp, WPqkv, qkv_b + (size_t)i * 3840, QKV, nullptr, 1280, 3840, 1024, nullptr);
    rope_vt_kernel<<<dim3(16, 16), 256, 0, stream>>>(QKV, COSb, SINb, Qp, Kp, Vt);
    if (i == 3 || i == 7)
      attn_f16<true ><<<dim3(16, 16), 256, 0, stream>>>(Qp, Kp, Vt, Op);
    else
      attn_f16<false><<<dim3(16, 16), 256, 0, stream>>>(Qp, Kp, Vt, Op);
    // proj: split-K2 (320 blocks) -> fused reduce(+bias+res) + ln2
    gemm_f16<0, 2, 64><<<dim3(10, 16, 2), 256, 0, stream>>>(
        Op, WPproj, nullptr, nullptr, nullptr, 1280, 1280, 1024, PART);
    reduce_rms<<<1024, 256, 0, stream>>>(PART, 2,
        proj_b + (size_t)i * 1280, H, H, ln2_w + (size_t)i * 1280, ANp);
    // fused gate+up (interleaved): 864 blocks, BK=32 (6/CU capacity)
    gemm_f16<4, 1, 32><<<dim3(54, 16), 256, 0, stream>>>(
        ANp, WPgu, BGU + (size_t)i * 6912, nullptr, DAp, 1280, 6912, 1024, nullptr);
    // down: split-K2 (320 blocks) -> fused reduce(+bias+res) + ln1(i+1)/lnq
    gemm_f16<0, 2, 64><<<dim3(10, 16, 2), 256, 0, stream>>>(
        DAp, WPdown, nullptr, nullptr, nullptr, 3456, 1280, 1024, PART);
    const float* next_w = (i == 7) ? lnq_w : (ln1_w + (size_t)(i + 1) * 1280);
    reduce_rms<<<1024, 256, 0, stream>>>(PART, 2,
        down_b + (size_t)i * 1280, H, H, next_w, ANp);
  }

  // merger
  // m1: 256x5120x5120, split-K4 (640 blocks, 2.5/CU <= 3 capacity), gelu
  convert_w_kernel<<<dim3(80, 80), 256, 0, stream>>>(m1_w, WP, 5120, 5120, 5120);
  gemm_f16<0, 4, 64><<<dim3(40, 4, 4), 256, 0, stream>>>(
      ANp, WP, nullptr, nullptr, nullptr, 5120, 5120, 256, PART);
  reduce_k<2><<<1280, 256, 0, stream>>>(PART, 4, 256, 5120, m1_b, nullptr, G1p, nullptr);
  // m2: 256x3584x5120, split-K4 (448 blocks), scatter rows
  convert_w_kernel<<<dim3(80, 56), 256, 0, stream>>>(m2_w, WP, 5120, 3584, 5120);
  gemm_f16<0, 4, 64><<<dim3(28, 4, 4), 256, 0, stream>>>(
      G1p, WP, nullptr, nullptr, nullptr, 5120, 3584, 256, PART);
  reduce_k<3><<<896, 256, 0, stream>>>(PART, 4, 256, 3584, m2_b, (float*)d_out, nullptr, win);
}

// Round 11
// 1344.884 us; speedup vs baseline: 1.3946x; 1.1465x over previous
//
#include <hip/hip_runtime.h>
#include <math.h>

typedef float  floatx4  __attribute__((ext_vector_type(4)));
typedef _Float16 half8  __attribute__((ext_vector_type(8)));
typedef _Float16 half4  __attribute__((ext_vector_type(4)));

// ---------- MFMA 16x16x32 f16 ----------
// A-frag: lane l holds A[l&15][(l>>4)*8+j]; B-frag: lane l holds B[(l>>4)*8+j][l&15]
// C/D: lane l reg e = D[(l>>4)*4+e][l&15]   (verified rounds 1-10)
__device__ inline floatx4 mfma_f16(half8 a, half8 b, floatx4 c){
  return __builtin_amdgcn_mfma_f32_16x16x32_f16(a, b, c, 0, 0, 0);
}

// ---------- async global->LDS, 16B per lane ----------
__device__ inline void gld_lds16(const void* g, void* l){
  __builtin_amdgcn_global_load_lds(
      (const __attribute__((address_space(1))) unsigned int*)g,
      (__attribute__((address_space(3))) unsigned int*)l, 16, 0, 0);
}

// =======================================================================
// fp16 GEMM, 256 threads (4 waves 2x2), tile 64x128, BK 32/64.
// Double-buffered LDS, gld_lds staging, granule-XOR swizzle, XCD swizzle.
// Modes: 0 outf=acc+bias (f32); 5 outp=acc+bias (fp16). KSPLIT>1 -> partials.
// =======================================================================
template<int MODE, int KSPLIT, int BK>
__global__ __launch_bounds__(256) void gemm_f16(
    const _Float16* __restrict__ A, const _Float16* __restrict__ W,
    const float* __restrict__ bias,
    float* __restrict__ outf, _Float16* __restrict__ outp,
    int K, int Nout, int Mtot, float* __restrict__ part)
{
  constexpr int BM = 64, BN = 128, GPR = BK / 8;
  __shared__ _Float16 SA[2][BM*BK];
  __shared__ _Float16 SW[2][BN*BK];
  const int tid = threadIdx.x, lane = tid & 63, wv = tid >> 6;
  const int wm = wv >> 1, wn = wv & 1;

  int m_idx, n_idx;
  {
    const int gx = gridDim.x, gy = gridDim.y;
    const int T = gx * gy;
    int id = blockIdx.y * gx + blockIdx.x;
    if ((T & 7) == 0){
      int wg = (id & 7) * (T >> 3) + (id >> 3);
      n_idx = wg / gy; m_idx = wg - n_idx * gy;
    } else { n_idx = blockIdx.x; m_idx = blockIdx.y; }
  }
  const int m0 = m_idx * BM, n0 = n_idx * BN;
  const int kbase = (KSPLIT > 1) ? blockIdx.z * (K / KSPLIT) : 0;
  floatx4 acc[2][4];
  #pragma unroll
  for (int mr = 0; mr < 2; mr++)
    #pragma unroll
    for (int nr = 0; nr < 4; nr++) acc[mr][nr] = 0.f;
  const int fr = lane & 15, kg = lane >> 4;

  auto stage = [&](int buf, int k0){
    #pragma unroll
    for (int p = 0; p < (BM * GPR) / 256; p++){
      int lin = p * 256 + tid;
      int row = lin / GPR, gi = lin % GPR;
      int gg = (BK == 64) ? (gi ^ (row & 7)) : (gi ^ ((row >> 1) & 3));
      size_t go = (size_t)(m0 + row) * K + kbase + k0 + gg * 8;
      gld_lds16(A + go, &SA[buf][(p * 256 + wv * 64) * 8]);
    }
    #pragma unroll
    for (int p = 0; p < (BN * GPR) / 256; p++){
      int lin = p * 256 + tid;
      int row = lin / GPR, gi = lin % GPR;
      int gg = (BK == 64) ? (gi ^ (row & 7)) : (gi ^ ((row >> 1) & 3));
      size_t go = (size_t)(n0 + row) * K + kbase + k0 + gg * 8;
      gld_lds16(W + go, &SW[buf][(p * 256 + wv * 64) * 8]);
    }
  };

  stage(0, 0);
  __syncthreads();
  const int nt = (K / KSPLIT) / BK;
  for (int t = 0; t < nt; t++){
    const int buf = t & 1;
    if (t + 1 < nt) stage(buf ^ 1, (t + 1) * BK);
    #pragma unroll
    for (int ks = 0; ks < BK / 32; ks++){
      half8 af[2], wf[4];
      #pragma unroll
      for (int mr = 0; mr < 2; mr++){
        int r = wm * 32 + mr * 16 + fr;
        int off = (BK == 64) ? r * 128 + (((ks * 4 + kg) ^ (r & 7)) << 4)
                             : r * 64  + ((kg ^ ((r >> 1) & 3)) << 4);
        af[mr] = *(const half8*)((const char*)&SA[buf][0] + off);
      }
      #pragma unroll
      for (int nr = 0; nr < 4; nr++){
        int r = wn * 64 + nr * 16 + fr;
        int off = (BK == 64) ? r * 128 + (((ks * 4 + kg) ^ (r & 7)) << 4)
                             : r * 64  + ((kg ^ ((r >> 1) & 3)) << 4);
        wf[nr] = *(const half8*)((const char*)&SW[buf][0] + off);
      }
      #pragma unroll
      for (int mr = 0; mr < 2; mr++)
        #pragma unroll
        for (int nr = 0; nr < 4; nr++)
          acc[mr][nr] = mfma_f16(af[mr], wf[nr], acc[mr][nr]);
    }
    __syncthreads();
  }
  #pragma unroll
  for (int mr = 0; mr < 2; mr++)
    #pragma unroll
    for (int nr = 0; nr < 4; nr++){
      int np = n0 + wn * 64 + nr * 16 + fr;
      #pragma unroll
      for (int e = 0; e < 4; e++){
        int row = m0 + wm * 32 + mr * 16 + kg * 4 + e;
        float v = acc[mr][nr][e];
        if (KSPLIT > 1){
          part[((size_t)blockIdx.z * Mtot + row) * Nout + np] = v;
        } else {
          v += bias ? bias[np] : 0.f;
          if (MODE == 0) outf[(size_t)row * Nout + np] = v;
          if (MODE == 5) outp[(size_t)row * Nout + np] = (_Float16)v;
        }
      }
    }
}

// =======================================================================
// Per-layer weight convert body (tight 1-D, 4840 blocks).
// Segments: [0,1200) qkv | [1200,1600) proj | [1600,2680) gate |
// [2680,3760) up | [3760,4840) down. WP layout (rows x Kpad):
// qkv [0,3840) K1280 | proj [3840,5120) K1280 | g/u interleaved
// [5120,12032) K1280 | down at elem 12032*1280, 1280 x K3456.
// =======================================================================
__device__ inline void convert_layer_body(int bid, float (*T)[68],
    const float* __restrict__ qkv_w, const float* __restrict__ proj_w,
    const float* __restrict__ gate_w, const float* __restrict__ up_w,
    const float* __restrict__ down_w, _Float16* __restrict__ WP)
{
  const float* Ws; int Nstride, n0, Kpad, rmul, radd, kb; size_t dbase;
  if (bid < 1200){
    int l = bid; kb = l % 20; int nb = l / 20;
    Ws = qkv_w;  Nstride = 3840; n0 = nb * 64; Kpad = 1280;
    dbase = 0; rmul = 1; radd = 0;
  } else if (bid < 1600){
    int l = bid - 1200; kb = l % 20; int nb = l / 20;
    Ws = proj_w; Nstride = 1280; n0 = nb * 64; Kpad = 1280;
    dbase = 3840ull * 1280; rmul = 1; radd = 0;
  } else if (bid < 2680){
    int l = bid - 1600; kb = l % 20; int nb = l / 20;
    Ws = gate_w; Nstride = 3456; n0 = nb * 64; Kpad = 1280;
    dbase = 5120ull * 1280; rmul = 2; radd = 0;
  } else if (bid < 3760){
    int l = bid - 2680; kb = l % 20; int nb = l / 20;
    Ws = up_w;   Nstride = 3456; n0 = nb * 64; Kpad = 1280;
    dbase = 5120ull * 1280; rmul = 2; radd = 1;
  } else {
    int l = bid - 3760; kb = l % 54; int nb = l / 54;
    Ws = down_w; Nstride = 1280; n0 = nb * 64; Kpad = 3456;
    dbase = 12032ull * 1280; rmul = 1; radd = 0;
  }
  const int tid = threadIdx.x;
  const int k0 = kb * 64;
  const int kr = tid >> 4, nc = (tid & 15) << 2;
  #pragma unroll
  for (int p = 0; p < 4; p++){
    int k = k0 + p * 16 + kr;
    floatx4 v = *(const floatx4*)(Ws + (size_t)k * Nstride + n0 + nc);
    *(floatx4*)&T[p * 16 + kr][nc] = v;
  }
  __syncthreads();
  const int n = tid >> 2, kc = (tid & 3) << 4;
  half8 h0, h1;
  #pragma unroll
  for (int j = 0; j < 8; j++){
    h0[j] = (_Float16)T[kc + j][n];
    h1[j] = (_Float16)T[kc + 8 + j][n];
  }
  size_t ro = dbase + (size_t)((n0 + n) * rmul + radd) * Kpad + k0 + kc;
  *(half8*)&WP[ro] = h0; *(half8*)&WP[ro + 8] = h1;
}

__global__ __launch_bounds__(256) void convert_layer_kernel(
    const float* __restrict__ qkv_w, const float* __restrict__ proj_w,
    const float* __restrict__ gate_w, const float* __restrict__ up_w,
    const float* __restrict__ down_w, _Float16* __restrict__ WP)
{
  __shared__ float T[64][68];
  convert_layer_body(blockIdx.x, T, qkv_w, proj_w, gate_w, up_w, down_w, WP);
}

// =======================================================================
// MERGED: gate+up GEMM (blocks [0,864), BK=32, silu epilogue) +
// next layer's convert (blocks [864,5704)). Dynamic LDS (24576 B).
// =======================================================================
__global__ __launch_bounds__(256) void gu_conv(
    const _Float16* __restrict__ A, const _Float16* __restrict__ W,
    const float* __restrict__ bias, _Float16* __restrict__ outp,
    const float* __restrict__ nqkv, const float* __restrict__ nproj,
    const float* __restrict__ ngate, const float* __restrict__ nup,
    const float* __restrict__ ndown, _Float16* __restrict__ WPn,
    int has_conv)
{
  extern __shared__ char sm[];
  const int bid = blockIdx.x;
  if (bid >= 864){
    if (has_conv)
      convert_layer_body(bid - 864, (float(*)[68])sm,
                         nqkv, nproj, ngate, nup, ndown, WPn);
    return;
  }
  _Float16* SA = (_Float16*)sm;        // [2][64*32]
  _Float16* SW = SA + 2 * 64 * 32;     // [2][128*32]
  const int tid = threadIdx.x, lane = tid & 63, wv = tid >> 6;
  const int wm = wv >> 1, wn = wv & 1;
  int wg = (bid & 7) * 108 + (bid >> 3);
  int n_idx = wg / 16, m_idx = wg - n_idx * 16;
  const int m0 = m_idx * 64, n0 = n_idx * 128;
  const int K = 1280;
  floatx4 acc[2][4];
  #pragma unroll
  for (int mr = 0; mr < 2; mr++)
    #pragma unroll
    for (int nr = 0; nr < 4; nr++) acc[mr][nr] = 0.f;
  const int fr = lane & 15, kg = lane >> 4;

  auto stage = [&](int buf, int k0){
    { int row = tid >> 2, gi = tid & 3;
      int gg = gi ^ ((row >> 1) & 3);
      gld_lds16(A + (size_t)(m0 + row) * K + k0 + gg * 8,
                SA + buf * 2048 + (wv * 64) * 8); }
    #pragma unroll
    for (int p = 0; p < 2; p++){
      int lin = p * 256 + tid;
      int row = lin >> 2, gi = lin & 3;
      int gg = gi ^ ((row >> 1) & 3);
      gld_lds16(W + (size_t)(n0 + row) * K + k0 + gg * 8,
                SW + buf * 4096 + (p * 256 + wv * 64) * 8);
    }
  };

  stage(0, 0);
  __syncthreads();
  for (int t = 0; t < 40; t++){
    const int buf = t & 1;
    if (t + 1 < 40) stage(buf ^ 1, (t + 1) * 32);
    half8 af[2], wf[4];
    #pragma unroll
    for (int mr = 0; mr < 2; mr++){
      int r = wm * 32 + mr * 16 + fr;
      int off = r * 64 + ((kg ^ ((r >> 1) & 3)) << 4);
      af[mr] = *(const half8*)((const char*)(SA + buf * 2048) + off);
    }
    #pragma unroll
    for (int nr = 0; nr < 4; nr++){
      int r = wn * 64 + nr * 16 + fr;
      int off = r * 64 + ((kg ^ ((r >> 1) & 3)) << 4);
      wf[nr] = *(const half8*)((const char*)(SW + buf * 4096) + off);
    }
    #pragma unroll
    for (int mr = 0; mr < 2; mr++)
      #pragma unroll
      for (int nr = 0; nr < 4; nr++)
        acc[mr][nr] = mfma_f16(af[mr], wf[nr], acc[mr][nr]);
    __syncthreads();
  }
  #pragma unroll
  for (int mr = 0; mr < 2; mr++)
    #pragma unroll
    for (int nr = 0; nr < 4; nr++){
      int np = n0 + wn * 64 + nr * 16 + fr;
      #pragma unroll
      for (int e = 0; e < 4; e++){
        int row = m0 + wm * 32 + mr * 16 + kg * 4 + e;
        float v = acc[mr][nr][e] + bias[np];
        float pv = __shfl_xor(v, 1);
        if (!(fr & 1)){
          float dv = v / (1.f + __expf(-v)) * pv;
          outp[(size_t)row * 3456 + (np >> 1)] = (_Float16)dv;
        }
      }
    }
}

// =======================================================================
// Fused split-K reduce (+bias +res) -> H (f32) -> RMSNorm -> fp16 plane.
// =======================================================================
__global__ __launch_bounds__(256) void reduce_rms(
    const float* __restrict__ part, int Z,
    const float* __restrict__ bias, const float* __restrict__ res,
    float* __restrict__ Hout, const float* __restrict__ w,
    _Float16* __restrict__ ANp)
{
  const int row = blockIdx.x;
  float v[5];
  float ss = 0.f;
  #pragma unroll
  for (int j = 0; j < 5; j++){
    int col = threadIdx.x + j * 256;
    float t = part[(size_t)row * 1280 + col];
    for (int z = 1; z < Z; z++)
      t += part[((size_t)z * 1024 + row) * 1280 + col];
    if (bias) t += bias[col];
    if (res)  t += res[(size_t)row * 1280 + col];
    v[j] = t;
    Hout[(size_t)row * 1280 + col] = t;
    ss = fmaf(t, t, ss);
  }
  for (int o = 32; o > 0; o >>= 1) ss += __shfl_down(ss, o);
  __shared__ float wsum[4];
  __shared__ float snorm;
  if ((threadIdx.x & 63) == 0) wsum[threadIdx.x >> 6] = ss;
  __syncthreads();
  if (threadIdx.x == 0){
    float t = wsum[0] + wsum[1] + wsum[2] + wsum[3];
    snorm = 1.0f / sqrtf(t * (1.0f / 1280.0f) + 1e-6f);
  }
  __syncthreads();
  float s = snorm;
  #pragma unroll
  for (int j = 0; j < 5; j++){
    int col = threadIdx.x + j * 256;
    ANp[(size_t)row * 1280 + col] = (_Float16)(v[j] * s * w[col]);
  }
}

// =======================================================================
// Generic split-K reduce + epilogue (merger).
// MODE 2: outp(fp16) = gelu_exact(sum+bias); MODE 3: row-scatter f32.
// =======================================================================
template<int MODE>
__global__ __launch_bounds__(256) void reduce_k(
    const float* __restrict__ part, int Z, int M, int N,
    const float* __restrict__ bias,
    float* __restrict__ outf, _Float16* __restrict__ outp,
    const int* __restrict__ rowmap)
{
  int idx4 = (blockIdx.x * 256 + threadIdx.x) * 4;
  if (idx4 >= M * N) return;
  int row = idx4 / N, col = idx4 - row * N;
  floatx4 v = *(const floatx4*)(part + (size_t)row * N + col);
  for (int z = 1; z < Z; z++){
    floatx4 p = *(const floatx4*)(part + ((size_t)z * M + row) * N + col);
    v[0] += p[0]; v[1] += p[1]; v[2] += p[2]; v[3] += p[3];
  }
  if (bias){
    floatx4 b = *(const floatx4*)(bias + col);
    v[0] += b[0]; v[1] += b[1]; v[2] += b[2]; v[3] += b[3];
  }
  if (MODE == 2){
    half4 h;
    #pragma unroll
    for (int j = 0; j < 4; j++){
      float g = 0.5f * v[j] * (1.f + erff(v[j] * 0.70710678118654752f));
      h[j] = (_Float16)g;
    }
    *(half4*)(outp + (size_t)row * N + col) = h;
  } else {
    *(floatx4*)(outf + (size_t)rowmap[row] * N + col) = v;
  }
}

// =======================================================================
// Standalone weight convert (patch / m1 / m2): f32 [K][Nstride] ->
// transposed fp16 plane [N][Kpad], zero-pad k>=K.
// =======================================================================
__global__ __launch_bounds__(256) void convert_w_kernel(
    const float* __restrict__ W, _Float16* __restrict__ PH,
    int K, int Nstride, int Kpad)
{
  __shared__ float T[64][68];
  const int tid = threadIdx.x;
  const int k0 = blockIdx.x * 64, n0 = blockIdx.y * 64;
  const int kr = tid >> 4, nc = (tid & 15) << 2;
  #pragma unroll
  for (int p = 0; p < 4; p++){
    int k = k0 + p * 16 + kr;
    floatx4 v = {0.f, 0.f, 0.f, 0.f};
    if (k < K) v = *(const floatx4*)(W + (size_t)k * Nstride + n0 + nc);
    *(floatx4*)&T[p * 16 + kr][nc] = v;
  }
  __syncthreads();
  const int n = tid >> 2, kc = (tid & 3) << 4;
  half8 h0, h1;
  #pragma unroll
  for (int j = 0; j < 8; j++){
    h0[j] = (_Float16)T[kc + j][n];
    h1[j] = (_Float16)T[kc + 8 + j][n];
  }
  size_t ro = (size_t)(n0 + n) * Kpad + k0 + kc;
  *(half8*)&PH[ro] = h0; *(half8*)&PH[ro + 8] = h1;
}

// =======================================================================
// Patch gather (window perm folded) -> fp16 plane [1024][1280] (zero-pad)
// =======================================================================
__global__ __launch_bounds__(256) void gather_x_kernel(
    const float* __restrict__ img, const int* __restrict__ win,
    _Float16* __restrict__ Xp)
{
  int idx = blockIdx.x * 256 + threadIdx.x;
  if (idx >= 1024 * 1280) return;
  int s = idx / 1280, f = idx - s * 1280;
  float val = 0.f;
  if (f < 1176){
    int sp = (win[s >> 2] << 2) | (s & 3);
    int i0 = sp >> 6, r = sp & 63;
    int i3 = r >> 2, rr = r & 3, i1 = rr >> 1, i4 = rr & 1;
    int c  = f / 392, f2 = f - c * 392;
    int f3 = f2 % 196;
    int ph = f3 / 14, pw2 = f3 - ph * 14;
    int hp = (i0 * 2 + i1) * 14 + ph, wp = (i3 * 2 + i4) * 14 + pw2;
    val = img[((size_t)c * 448 + hp) * 448 + wp];
  }
  Xp[idx] = (_Float16)val;
}

__global__ __launch_bounds__(256) void rope_tables_kernel(
    const float* __restrict__ rpe, const int* __restrict__ win,
    float* __restrict__ cosb, float* __restrict__ sinb)
{
  int idx = blockIdx.x * 256 + threadIdx.x;
  if (idx >= 1024 * 80) return;
  int s = idx / 80, d = idx - s * 80;
  int src = (win[s >> 2] << 2) | (s & 3);
  float ang = rpe[src * 40 + (d % 40)];
  cosb[idx] = cosf(ang);
  sinb[idx] = sinf(ang);
}

// =======================================================================
// Fused RoPE(Q,K) + V-transpose (FULL layers only). QKV fp16 [1024][3840].
// =======================================================================
__global__ __launch_bounds__(256) void rope_vt_kernel(
    const _Float16* __restrict__ qkv,
    const float* __restrict__ cosb, const float* __restrict__ sinb,
    _Float16* __restrict__ Qp, _Float16* __restrict__ Kp,
    _Float16* __restrict__ Vt)
{
  __shared__ _Float16 T[64][81];
  const int h = blockIdx.y, s0 = blockIdx.x * 64;
  for (int c = threadIdx.x; c < 64 * 128; c += 256){
    int sl = c >> 7, d = c & 127;
    int s = s0 + sl;
    size_t o = ((size_t)h * 1024 + s) * 128 + d;
    if (d >= 80){ Qp[o] = (_Float16)0.f; Kp[o] = (_Float16)0.f; continue; }
    const _Float16* base = qkv + (size_t)s * 3840;
    float qv = (float)base[h * 80 + d], kv = (float)base[1280 + h * 80 + d];
    float qo = (d < 40) ? -(float)base[h * 80 + d + 40] : (float)base[h * 80 + d - 40];
    float ko = (d < 40) ? -(float)base[1280 + h * 80 + d + 40] : (float)base[1280 + h * 80 + d - 40];
    float cc = cosb[s * 80 + d], sn = sinb[s * 80 + d];
    Qp[o] = (_Float16)((qv * cc + qo * sn) * 0.11180339887498949f);
    Kp[o] = (_Float16)(kv * cc + ko * sn);
  }
  for (int c = threadIdx.x; c < 64 * 80; c += 256){
    int sl = c / 80, d = c - sl * 80;
    T[sl][d] = qkv[(size_t)(s0 + sl) * 3840 + 2560 + h * 80 + d];
  }
  __syncthreads();
  for (int c = threadIdx.x; c < 80 * 64; c += 256){
    int d = c >> 6, sl = c & 63;
    Vt[((size_t)h * 80 + d) * 1024 + s0 + sl] = T[sl][d];
  }
}

// concat gate_b/up_b interleaved -> [8][6912]
__global__ __launch_bounds__(256) void concat_bias_kernel(
    const float* __restrict__ gb, const float* __restrict__ ub, float* __restrict__ out)
{
  int idx = blockIdx.x * 256 + threadIdx.x;
  if (idx >= 8 * 6912) return;
  int l = idx / 6912, j = idx - l * 6912;
  out[idx] = (j & 1) ? ub[l * 3456 + (j >> 1)] : gb[l * 3456 + (j >> 1)];
}

// =======================================================================
// Fused WINDOW attention: RoPE + QK^T + softmax + PV for one 64-token
// block-diagonal tile x head. No Q/K/V HBM round-trip.
// =======================================================================
__global__ __launch_bounds__(256) void attn_win_fused(
    const _Float16* __restrict__ qkv,
    const float* __restrict__ cosb, const float* __restrict__ sinb,
    _Float16* __restrict__ Op)
{
  __shared__ _Float16 KT[64 * 128];   // swizzled K rows
  __shared__ _Float16 VS[80 * 64];    // swizzled V^T rows
  __shared__ _Float16 PS[64 * 72];    // P (LD=72)
  const int tid = threadIdx.x, lane = tid & 63, wv = tid >> 6;
  const int qb = blockIdx.x, h = blockIdx.y;
  const int fr = lane & 15, kg = lane >> 4;
  const int s0 = qb * 64;

  // ---- K rope -> KT (64 rows x 16 granules; g>=10 zero-pad)
  for (int it = tid; it < 1024; it += 256){
    int row = it >> 4, g = it & 15;
    half8 out = {};
    if (g < 10){
      int d0 = g * 8;
      const _Float16* kb = qkv + (size_t)(s0 + row) * 3840 + 1280 + h * 80;
      half8 k8 = *(const half8*)(kb + d0);
      int dp = (d0 < 40) ? d0 + 40 : d0 - 40;
      half8 kp = *(const half8*)(kb + dp);
      const float* cb = cosb + (size_t)(s0 + row) * 80 + d0;
      const float* sb = sinb + (size_t)(s0 + row) * 80 + d0;
      float sgn = (d0 < 40) ? -1.f : 1.f;
      #pragma unroll
      for (int j = 0; j < 8; j++)
        out[j] = (_Float16)((float)k8[j] * cb[j] + sgn * (float)kp[j] * sb[j]);
    }
    *(half8*)((char*)KT + row * 256 + ((g * 16) ^ ((row & 7) << 4))) = out;
  }
  // ---- V -> VS^T (64 rows x 10 d-granules; coalesced read, scalar writes)
  for (int it = tid; it < 640; it += 256){
    int row = it / 10, gd = it - (it / 10) * 10;
    int d0 = gd * 8;
    half8 v8 = *(const half8*)(qkv + (size_t)(s0 + row) * 3840 + 2560 + h * 80 + d0);
    #pragma unroll
    for (int j = 0; j < 8; j++){
      int d = d0 + j;
      int byte = d * 128 + (((row >> 3) << 4) ^ ((d & 7) << 4)) + (row & 7) * 2;
      *(_Float16*)((char*)VS + byte) = v8[j];
    }
  }
  // ---- Q rope in registers (row wv*16+fr, d0 = ks*32+kg*8), pre-scaled
  half8 qf[3];
  {
    int row = s0 + wv * 16 + fr;
    const _Float16* qb_ = qkv + (size_t)row * 3840 + h * 80;
    const float* cb = cosb + (size_t)row * 80;
    const float* sb = sinb + (size_t)row * 80;
    #pragma unroll
    for (int ks = 0; ks < 3; ks++){
      int d0 = ks * 32 + kg * 8;
      half8 out = {};
      if (d0 < 80){
        half8 q8 = *(const half8*)(qb_ + d0);
        int dp = (d0 < 40) ? d0 + 40 : d0 - 40;
        half8 qp = *(const half8*)(qb_ + dp);
        float sgn = (d0 < 40) ? -1.f : 1.f;
        #pragma unroll
        for (int j = 0; j < 8; j++)
          out[j] = (_Float16)(((float)q8[j] * cb[d0 + j] +
                               sgn * (float)qp[j] * sb[d0 + j]) * 0.11180339887498949f);
      }
      qf[ks] = out;
    }
  }
  __syncthreads();
  // ---- S = Q K^T (64x64)
  floatx4 accS[4];
  #pragma unroll
  for (int c = 0; c < 4; c++) accS[c] = 0.f;
  #pragma unroll
  for (int c = 0; c < 4; c++){
    int row = c * 16 + fr;
    #pragma unroll
    for (int ks = 0; ks < 3; ks++){
      int off = row * 256 + ((ks * 64 + kg * 16) ^ ((row & 7) << 4));
      half8 kf = *(const half8*)((const char*)KT + off);
      accS[c] = mfma_f16(qf[ks], kf, accS[c]);
    }
  }
  // ---- full-row softmax
  float linv_[4];
  #pragma unroll
  for (int r = 0; r < 4; r++){
    float mx = fmaxf(fmaxf(accS[0][r], accS[1][r]), fmaxf(accS[2][r], accS[3][r]));
    mx = fmaxf(mx, __shfl_xor(mx, 1)); mx = fmaxf(mx, __shfl_xor(mx, 2));
    mx = fmaxf(mx, __shfl_xor(mx, 4)); mx = fmaxf(mx, __shfl_xor(mx, 8));
    float ls = 0.f;
    #pragma unroll
    for (int c = 0; c < 4; c++){
      float p = __expf(accS[c][r] - mx);
      ls += p;
      PS[(wv * 16 + kg * 4 + r) * 72 + c * 16 + fr] = (_Float16)p;
    }
    ls += __shfl_xor(ls, 1); ls += __shfl_xor(ls, 2);
    ls += __shfl_xor(ls, 4); ls += __shfl_xor(ls, 8);
    linv_[r] = 1.f / ls;
  }
  __syncthreads();
  // ---- O = P V
  floatx4 oa[5];
  #pragma unroll
  for (int nb = 0; nb < 5; nb++) oa[nb] = 0.f;
  half8 pa[2];
  #pragma unroll
  for (int ks = 0; ks < 2; ks++)
    pa[ks] = *(const half8*)((const char*)PS + (wv * 16 + fr) * 144 + ks * 64 + kg * 16);
  #pragma unroll
  for (int nb = 0; nb < 5; nb++){
    int row = nb * 16 + fr;
    #pragma unroll
    for (int ks = 0; ks < 2; ks++){
      int off = row * 128 + ((ks * 64 + kg * 16) ^ ((row & 7) << 4));
      half8 vf = *(const half8*)((const char*)VS + off);
      oa[nb] = mfma_f16(pa[ks], vf, oa[nb]);
    }
  }
  #pragma unroll
  for (int nb = 0; nb < 5; nb++)
    #pragma unroll
    for (int r = 0; r < 4; r++){
      size_t o = (size_t)(s0 + wv * 16 + kg * 4 + r) * 1280 + h * 80 + nb * 16 + fr;
      Op[o] = (_Float16)(oa[nb][r] * linv_[r]);
    }
}

// =======================================================================
// fp16 MFMA flash attention (FULL layers). 4 waves, KVBLK=32.
// =======================================================================
template<bool FULL>
__global__ __launch_bounds__(256) void attn_f16(
    const _Float16* __restrict__ Qp, const _Float16* __restrict__ Kp,
    const _Float16* __restrict__ Vt, _Float16* __restrict__ Op)
{
  __shared__ _Float16 KT[2][32 * 128];
  __shared__ _Float16 VS[2][80 * 32];
  __shared__ _Float16 PS[64 * 40];
  const int tid = threadIdx.x, lane = tid & 63, wv = tid >> 6;
  const int qb = blockIdx.x, h = blockIdx.y;
  const int fr = lane & 15, kg = lane >> 4;

  half8 qf[3];
  {
    size_t qbase = ((size_t)h * 1024 + qb * 64 + wv * 16 + fr) * 128;
    #pragma unroll
    for (int ks = 0; ks < 3; ks++)
      qf[ks] = *(const half8*)(Qp + qbase + ks * 32 + kg * 8);
  }
  float m_r[4], l_r[4];
  #pragma unroll
  for (int r = 0; r < 4; r++){ m_r[r] = -3e38f; l_r[r] = 0.f; }
  floatx4 oa[5];
  #pragma unroll
  for (int nb = 0; nb < 5; nb++) oa[nb] = 0.f;

  const int nt  = FULL ? 32 : 2;
  const int kt0 = FULL ? 0 : qb * 2;

  auto stageK = [&](int buf, int kt){
    #pragma unroll
    for (int p = 0; p < 2; p++){
      int lin = p * 256 + tid;
      int row = lin >> 4, gg = (lin & 15) ^ (row & 7);
      size_t go = ((size_t)h * 1024 + kt * 32 + row) * 128 + gg * 8;
      gld_lds16(Kp + go, &KT[buf][(p * 256 + wv * 64) * 8]);
    }
    #pragma unroll
    for (int p = 0; p < 2; p++){
      int lin = p * 256 + tid;
      if (lin < 320){
        int row = lin >> 2, gg = (lin & 3) ^ (row & 3);
        size_t go = ((size_t)h * 80 + row) * 1024 + kt * 32 + gg * 8;
        gld_lds16(Vt + go, &VS[buf][(p * 256 + wv * 64) * 8]);
      }
    }
  };

  stageK(0, kt0);
  __syncthreads();
  for (int t = 0; t < nt; t++){
    const int buf = t & 1;
    if (t + 1 < nt) stageK(buf ^ 1, kt0 + t + 1);
    floatx4 accS[2];
    accS[0] = 0.f; accS[1] = 0.f;
    #pragma unroll
    for (int c = 0; c < 2; c++){
      #pragma unroll
      for (int ks = 0; ks < 3; ks++){
        int row = c * 16 + fr;
        int off = row * 256 + ((ks * 64 + kg * 16) ^ ((row & 7) << 4));
        half8 kf = *(const half8*)((const char*)&KT[buf][0] + off);
        accS[c] = mfma_f16(qf[ks], kf, accS[c]);
      }
    }
    float corr[4], ps_[4];
    #pragma unroll
    for (int r = 0; r < 4; r++){
      float v = fmaxf(accS[0][r], accS[1][r]);
      v = fmaxf(v, __shfl_xor(v, 1)); v = fmaxf(v, __shfl_xor(v, 2));
      v = fmaxf(v, __shfl_xor(v, 4)); v = fmaxf(v, __shfl_xor(v, 8));
      float mn = fmaxf(m_r[r], v);
      corr[r] = __expf(m_r[r] - mn);
      m_r[r] = mn;
      ps_[r] = 0.f;
    }
    #pragma unroll
    for (int c = 0; c < 2; c++)
      #pragma unroll
      for (int r = 0; r < 4; r++){
        float p = __expf(accS[c][r] - m_r[r]);
        ps_[r] += p;
        PS[(wv * 16 + kg * 4 + r) * 40 + c * 16 + fr] = (_Float16)p;
      }
    #pragma unroll
    for (int r = 0; r < 4; r++){
      float v = ps_[r];
      v += __shfl_xor(v, 1); v += __shfl_xor(v, 2);
      v += __shfl_xor(v, 4); v += __shfl_xor(v, 8);
      l_r[r] = l_r[r] * corr[r] + v;
      #pragma unroll
      for (int nb = 0; nb < 5; nb++) oa[nb][r] *= corr[r];
    }
    {
      int poff = (wv * 16 + fr) * 80 + kg * 16;
      half8 pa = *(const half8*)((const char*)&PS[0] + poff);
      #pragma unroll
      for (int nb = 0; nb < 5; nb++){
        int row = nb * 16 + fr;
        int off = row * 64 + ((kg * 16) ^ ((row & 3) << 4));
        half8 vf = *(const half8*)((const char*)&VS[buf][0] + off);
        oa[nb] = mfma_f16(pa, vf, oa[nb]);
      }
    }
    __syncthreads();
  }
  float linv[4];
  #pragma unroll
  for (int r = 0; r < 4; r++) linv[r] = 1.f / l_r[r];
  #pragma unroll
  for (int nb = 0; nb < 5; nb++)
    #pragma unroll
    for (int r = 0; r < 4; r++){
      float v = oa[nb][r] * linv[r];
      size_t o = (size_t)(qb * 64 + wv * 16 + kg * 4 + r) * 1280 + h * 80 + nb * 16 + fr;
      Op[o] = (_Float16)v;
    }
}

// =======================================================================
extern "C" void kernel_launch(void* const* d_in, const int* in_sizes, int n_in,
                              void* d_out, int out_size, void* d_ws, size_t ws_size,
                              hipStream_t stream)
{
  (void)in_sizes; (void)n_in; (void)out_size;
  const float* images  = (const float*)d_in[0];
  const int*   win     = (const int*)  d_in[1];
  const float* rpe     = (const float*)d_in[3];
  const float* patch_w = (const float*)d_in[6];
  const float* ln1_w   = (const float*)d_in[7];
  const float* ln2_w   = (const float*)d_in[8];
  const float* qkv_w   = (const float*)d_in[9];
  const float* qkv_b   = (const float*)d_in[10];
  const float* proj_w  = (const float*)d_in[11];
  const float* proj_b  = (const float*)d_in[12];
  const float* gate_w  = (const float*)d_in[13];
  const float* gate_b  = (const float*)d_in[14];
  const float* up_w    = (const float*)d_in[15];
  const float* up_b    = (const float*)d_in[16];
  const float* down_w  = (const float*)d_in[17];
  const float* down_b  = (const float*)d_in[18];
  const float* lnq_w   = (const float*)d_in[19];
  const float* m1_w    = (const float*)d_in[20];
  const float* m1_b    = (const float*)d_in[21];
  const float* m2_w    = (const float*)d_in[22];
  const float* m2_b    = (const float*)d_in[23];

  char* ws = (char*)d_ws;
  size_t off = 0;
  auto alloc = [&](size_t b){ size_t o = off; off += (b + 255) & ~(size_t)255; return o; };
  _Float16* WPa = (_Float16*)(ws + alloc(26214400ull * 2));   // 52.4MB (layers even + m1)
  _Float16* WPb = (_Float16*)(ws + alloc(19865600ull * 2));   // 39.7MB (layers odd + patch + m2)
  float* PART = (float*)(ws + alloc(22020096ull));            // 21MB
  _Float16* Xp  = (_Float16*)(ws + alloc(1024ull * 1280 * 2));
  _Float16* ANp = (_Float16*)(ws + alloc(1024ull * 1280 * 2));
  float* H    = (float*)(ws + alloc(1024ull * 1280 * 4));
  _Float16* QKVh = (_Float16*)(ws + alloc(1024ull * 3840 * 2));
  _Float16* Qp = (_Float16*)(ws + alloc(16ull * 1024 * 128 * 2));
  _Float16* Kp = (_Float16*)(ws + alloc(16ull * 1024 * 128 * 2));
  _Float16* Vt = (_Float16*)(ws + alloc(16ull * 80 * 1024 * 2));
  _Float16* Op  = (_Float16*)(ws + alloc(1024ull * 1280 * 2));
  _Float16* DAp = (_Float16*)(ws + alloc(1024ull * 3456 * 2));
  _Float16* G1p = (_Float16*)(ws + alloc(256ull * 5120 * 2));
  float* COSb = (float*)(ws + alloc(1024ull * 80 * 4));
  float* SINb = (float*)(ws + alloc(1024ull * 80 * 4));
  float* BGU  = (float*)(ws + alloc(8ull * 6912 * 4));
  if (off > ws_size) return;

  gather_x_kernel   <<<5120, 256, 0, stream>>>(images, win, Xp);
  rope_tables_kernel<<<320,  256, 0, stream>>>(rpe, win, COSb, SINb);
  concat_bias_kernel<<<216,  256, 0, stream>>>(gate_b, up_b, BGU);

  // patch plane -> WPb; layer-0 planes -> WPa
  convert_w_kernel<<<dim3(20, 20), 256, 0, stream>>>(patch_w, WPb, 1176, 1280, 1280);
  convert_layer_kernel<<<4840, 256, 0, stream>>>(
      qkv_w, proj_w, gate_w, up_w, down_w, WPa);

  // patch embed: split-K2 -> fused reduce + ln1(0)
  gemm_f16<0, 2, 64><<<dim3(10, 16, 2), 256, 0, stream>>>(
      Xp, WPb, nullptr, nullptr, nullptr, 1280, 1280, 1024, PART);
  reduce_rms<<<1024, 256, 0, stream>>>(PART, 2, nullptr, nullptr, H, ln1_w, ANp);

  for (int i = 0; i < 8; i++){
    _Float16* WPc = (i & 1) ? WPb : WPa;
    _Float16* WPn = (i & 1) ? WPa : WPb;
    const _Float16* WPqkv  = WPc;
    const _Float16* WPproj = WPc + 3840ull * 1280;
    const _Float16* WPgu   = WPc + 5120ull * 1280;
    const _Float16* WPdown = WPc + 12032ull * 1280;

    // qkv: fp16 out, bias fused
    gemm_f16<5, 1, 64><<<dim3(30, 16), 256, 0, stream>>>(
        ANp, WPqkv, qkv_b + (size_t)i * 3840, nullptr, QKVh, 1280, 3840, 1024, nullptr);
    if (i == 3 || i == 7){
      rope_vt_kernel<<<dim3(16, 16), 256, 0, stream>>>(QKVh, COSb, SINb, Qp, Kp, Vt);
      attn_f16<true><<<dim3(16, 16), 256, 0, stream>>>(Qp, Kp, Vt, Op);
    } else {
      attn_win_fused<<<dim3(16, 16), 256, 0, stream>>>(QKVh, COSb, SINb, Op);
    }
    // proj: split-K2 -> fused reduce(+bias+res) + ln2
    gemm_f16<0, 2, 64><<<dim3(10, 16, 2), 256, 0, stream>>>(
        Op, WPproj, nullptr, nullptr, nullptr, 1280, 1280, 1024, PART);
    reduce_rms<<<1024, 256, 0, stream>>>(PART, 2,
        proj_b + (size_t)i * 1280, H, H, ln2_w + (size_t)i * 1280, ANp);
    // gate+up GEMM merged with convert of layer i+1 (overlap HBM vs MFMA)
    {
      int has_conv = (i < 7) ? 1 : 0;
      int grid = has_conv ? 5704 : 864;
      const float* nq = qkv_w  + (size_t)(i + 1) * 1280 * 3840;
      const float* np_ = proj_w + (size_t)(i + 1) * 1280 * 1280;
      const float* ng = gate_w + (size_t)(i + 1) * 1280 * 3456;
      const float* nu = up_w   + (size_t)(i + 1) * 1280 * 3456;
      const float* nd = down_w + (size_t)(i + 1) * 3456 * 1280;
      gu_conv<<<grid, 256, 24576, stream>>>(
          ANp, WPgu, BGU + (size_t)i * 6912, DAp,
          (i < 7) ? nq : qkv_w, (i < 7) ? np_ : proj_w,
          (i < 7) ? ng : gate_w, (i < 7) ? nu : up_w,
          (i < 7) ? nd : down_w, WPn, has_conv);
    }
    // down: split-K2 -> fused reduce(+bias+res) + ln1(i+1)/lnq
    gemm_f16<0, 2, 64><<<dim3(10, 16, 2), 256, 0, stream>>>(
        DAp, WPdown, nullptr, nullptr, nullptr, 3456, 1280, 1024, PART);
    const float* next_w = (i == 7) ? lnq_w : (ln1_w + (size_t)(i + 1) * 1280);
    reduce_rms<<<1024, 256, 0, stream>>>(PART, 2,
        down_b + (size_t)i * 1280, H, H, next_w, ANp);
  }

  // merger
  convert_w_kernel<<<dim3(80, 80), 256, 0, stream>>>(m1_w, WPa, 5120, 5120, 5120);
  gemm_f16<0, 4, 64><<<dim3(40, 4, 4), 256, 0, stream>>>(
      ANp, WPa, nullptr, nullptr, nullptr, 5120, 5120, 256, PART);
  reduce_k<2><<<1280, 256, 0, stream>>>(PART, 4, 256, 5120, m1_b, nullptr, G1p, nullptr);
  convert_w_kernel<<<dim3(80, 56), 256, 0, stream>>>(m2_w, WPb, 5120, 3584, 5120);
  gemm_f16<0, 4, 64><<<dim3(28, 4, 4), 256, 0, stream>>>(
      G1p, WPb, nullptr, nullptr, nullptr, 5120, 3584, 256, PART);
  reduce_k<3><<<896, 256, 0, stream>>>(PART, 4, 256, 3584, m2_b, (float*)d_out, nullptr, win);
}